// Round 1
// baseline (7123.925 us; speedup 1.0000x reference)
//
#include <hip/hip_runtime.h>
#include <cmath>

#define IMG_DIM 512
#define D_MODEL 768
#define N_LAYER 12
#define D_INNER 1536
#define D_STATE 16
#define D_CONV 4
#define DT_RANK 48
#define BATCH 4
#define SEQ 256
#define M_TOK (BATCH * SEQ)               // 1024 token rows
#define XPROJ_N (DT_RANK + 2 * D_STATE)   // 80

__device__ __forceinline__ float softplus_f(float v) {
    return v > 20.f ? v : log1pf(expf(v));
}

// ---------------------------------------------------------------------------
// Generic fp32 GEMM: C[M,N] = A[M,K] @ B[K,N] (+ epilogue)
// 64x64 tile, BK=16, 256 threads, 4x4 accum per thread.
// M is always a multiple of 64 (1024); K a multiple of 16; N bounds-checked.
// EPI: 0 = store, 1 = bias+relu, 2 = bias+softplus, 3 = accumulate into C
// ---------------------------------------------------------------------------
template <int EPI>
__global__ __launch_bounds__(256) void gemm64(
    const float* __restrict__ A, int lda,
    const float* __restrict__ B, int ldb,
    float* __restrict__ C, int ldc,
    const float* __restrict__ bias,
    int N, int K)
{
    __shared__ float As[16][64];
    __shared__ float Bs[16][64];
    const int tid = threadIdx.x;
    const int tx = tid & 15, ty = tid >> 4;
    const int rowBase = blockIdx.x * 64;
    const int colBase = blockIdx.y * 64;
    const int ar = tid >> 2, ak = (tid & 3) * 4;   // A-tile loader coords
    const int br = tid >> 4, bc = (tid & 15) * 4;  // B-tile loader coords

    float acc[4][4] = {};

    for (int k0 = 0; k0 < K; k0 += 16) {
        float4 av = *(const float4*)&A[(size_t)(rowBase + ar) * lda + k0 + ak];
        As[ak + 0][ar] = av.x;
        As[ak + 1][ar] = av.y;
        As[ak + 2][ar] = av.z;
        As[ak + 3][ar] = av.w;

        int gcol = colBase + bc;
        float4 bv;
        if (gcol + 3 < N) {
            bv = *(const float4*)&B[(size_t)(k0 + br) * ldb + gcol];
        } else {
            const float* bp = &B[(size_t)(k0 + br) * ldb];
            bv.x = (gcol + 0 < N) ? bp[gcol + 0] : 0.f;
            bv.y = (gcol + 1 < N) ? bp[gcol + 1] : 0.f;
            bv.z = (gcol + 2 < N) ? bp[gcol + 2] : 0.f;
            bv.w = (gcol + 3 < N) ? bp[gcol + 3] : 0.f;
        }
        *(float4*)&Bs[br][bc] = bv;

        __syncthreads();
        #pragma unroll
        for (int k = 0; k < 16; ++k) {
            float4 a = *(const float4*)&As[k][ty * 4];
            float4 b = *(const float4*)&Bs[k][tx * 4];
            float am[4] = {a.x, a.y, a.z, a.w};
            float bm[4] = {b.x, b.y, b.z, b.w};
            #pragma unroll
            for (int i = 0; i < 4; ++i)
                #pragma unroll
                for (int j = 0; j < 4; ++j)
                    acc[i][j] = fmaf(am[i], bm[j], acc[i][j]);
        }
        __syncthreads();
    }

    #pragma unroll
    for (int i = 0; i < 4; ++i) {
        int r = rowBase + ty * 4 + i;
        #pragma unroll
        for (int j = 0; j < 4; ++j) {
            int c = colBase + tx * 4 + j;
            if (c >= N) continue;
            float v = acc[i][j];
            float* dst = &C[(size_t)r * ldc + c];
            if (EPI == 0) {
                *dst = v;
            } else if (EPI == 1) {
                v += bias[c];
                *dst = v > 0.f ? v : 0.f;
            } else if (EPI == 2) {
                v += bias[c];
                *dst = softplus_f(v);
            } else {
                *dst += v;
            }
        }
    }
}

// ---------------------------------------------------------------------------
// RMSNorm: one block per token row (768 cols), 256 threads x 3 elements
// ---------------------------------------------------------------------------
__global__ __launch_bounds__(256) void rmsnorm_k(
    const float* __restrict__ x, const float* __restrict__ w,
    float* __restrict__ o)
{
    const int row = blockIdx.x;
    const float* xr = x + (size_t)row * D_MODEL;
    float v[3];
    float s = 0.f;
    #pragma unroll
    for (int i = 0; i < 3; ++i) {
        v[i] = xr[threadIdx.x + i * 256];
        s = fmaf(v[i], v[i], s);
    }
    #pragma unroll
    for (int off = 32; off > 0; off >>= 1) s += __shfl_down(s, off);
    __shared__ float red[4];
    if ((threadIdx.x & 63) == 0) red[threadIdx.x >> 6] = s;
    __syncthreads();
    float tot = red[0] + red[1] + red[2] + red[3];
    float r = rsqrtf(tot * (1.f / D_MODEL) + 1e-5f);
    float* orow = o + (size_t)row * D_MODEL;
    #pragma unroll
    for (int i = 0; i < 3; ++i) {
        int c = threadIdx.x + i * 256;
        orow[c] = v[i] * r * w[c];
    }
}

// ---------------------------------------------------------------------------
// Causal depthwise conv (width 4, left pad 3) + bias + silu
// xz: [1024][3072] (xi = cols [0,1536)); out xc: [1024][1536]
// ---------------------------------------------------------------------------
__global__ __launch_bounds__(256) void conv_silu_k(
    const float* __restrict__ xz, const float* __restrict__ cw,
    const float* __restrict__ cb, float* __restrict__ xc)
{
    int idx = blockIdx.x * 256 + threadIdx.x;   // over 1024*1536
    int d = idx % D_INNER;
    int bt = idx / D_INNER;
    int t = bt & (SEQ - 1);
    int b = bt >> 8;
    float acc = cb[d];
    #pragma unroll
    for (int k = 0; k < 4; ++k) {
        int tt = t - 3 + k;
        if (tt >= 0)
            acc = fmaf(xz[(size_t)(b * SEQ + tt) * (2 * D_INNER) + d], cw[d * 4 + k], acc);
    }
    float sig = 1.f / (1.f + expf(-acc));
    xc[idx] = acc * sig;
}

// ---------------------------------------------------------------------------
// Selective scan: one thread per (b, d); 16-state recurrence over 256 steps.
// Fused epilogue: y = (scan_y + u*D) * silu(res)
// ---------------------------------------------------------------------------
__global__ __launch_bounds__(256) void scan_k(
    const float* __restrict__ delta,  // [1024][1536]
    const float* __restrict__ xc,     // [1024][1536] (u)
    const float* __restrict__ xdbl,   // [1024][80]  (B at 48, C at 64)
    const float* __restrict__ xz,     // [1024][3072] (res at col 1536+d)
    const float* __restrict__ A_log,  // [1536][16]
    const float* __restrict__ D_param,// [1536]
    float* __restrict__ y)            // [1024][1536]
{
    const int tid = threadIdx.x;
    const int nblk = D_INNER / 256;            // 6
    const int d = (blockIdx.x % nblk) * 256 + tid;
    const int b = blockIdx.x / nblk;

    float A[D_STATE], h[D_STATE];
    #pragma unroll
    for (int n = 0; n < D_STATE; ++n) {
        A[n] = -expf(A_log[(size_t)d * D_STATE + n]);
        h[n] = 0.f;
    }
    const float Dp = D_param[d];

    for (int t = 0; t < SEQ; ++t) {
        const int bt = b * SEQ + t;
        float dv = delta[(size_t)bt * D_INNER + d];
        float u = xc[(size_t)bt * D_INNER + d];
        const float* Bp = xdbl + (size_t)bt * XPROJ_N + DT_RANK;
        const float* Cp = Bp + D_STATE;
        float du = dv * u;
        float yv = 0.f;
        #pragma unroll
        for (int n = 0; n < D_STATE; ++n) {
            float dA = expf(dv * A[n]);
            h[n] = fmaf(dA, h[n], du * Bp[n]);
            yv = fmaf(h[n], Cp[n], yv);
        }
        float res = xz[(size_t)bt * (2 * D_INNER) + D_INNER + d];
        float sr = res / (1.f + expf(-res));
        y[(size_t)bt * D_INNER + d] = (yv + u * Dp) * sr;
    }
}

// ---------------------------------------------------------------------------
// Launch
// ---------------------------------------------------------------------------
extern "C" void kernel_launch(void* const* d_in, const int* in_sizes, int n_in,
                              void* d_out, int out_size, void* d_ws, size_t ws_size,
                              hipStream_t stream)
{
    const float* frames  = (const float*)d_in[0];
    const float* fproj_w = (const float*)d_in[1];
    const float* fproj_b = (const float*)d_in[2];
    const float* norm_w  = (const float*)d_in[3];
    const float* in_w    = (const float*)d_in[4];
    const float* conv_w  = (const float*)d_in[5];
    const float* conv_b  = (const float*)d_in[6];
    const float* xproj_w = (const float*)d_in[7];
    const float* dt_w    = (const float*)d_in[8];
    const float* dt_b    = (const float*)d_in[9];
    const float* A_log   = (const float*)d_in[10];
    const float* D_param = (const float*)d_in[11];
    const float* out_w   = (const float*)d_in[12];
    const float* normf_w = (const float*)d_in[13];

    // workspace layout (floats); total ~9.4M floats (~38 MB)
    float* ws = (float*)d_ws;
    float* h     = ws;                          // 1024*768
    float* x     = h + M_TOK * D_MODEL;         // 1024*768
    float* xz    = x + M_TOK * D_MODEL;         // 1024*3072
    float* xc    = xz + M_TOK * 2 * D_INNER;    // 1024*1536
    float* xdbl  = xc + M_TOK * D_INNER;        // 1024*80
    float* delta = xdbl + M_TOK * XPROJ_N;      // 1024*1536
    float* y     = delta + M_TOK * D_INNER;     // 1024*1536

    dim3 blk(256);

    // h = relu(frames @ fproj_w + fproj_b)
    gemm64<1><<<dim3(M_TOK / 64, D_MODEL / 64), blk, 0, stream>>>(
        frames, IMG_DIM, fproj_w, D_MODEL, h, D_MODEL, fproj_b, D_MODEL, IMG_DIM);

    for (int i = 0; i < N_LAYER; ++i) {
        const float* in_wi    = in_w    + (size_t)i * D_MODEL * 2 * D_INNER;
        const float* conv_wi  = conv_w  + (size_t)i * D_INNER * D_CONV;
        const float* conv_bi  = conv_b  + (size_t)i * D_INNER;
        const float* xproj_wi = xproj_w + (size_t)i * D_INNER * XPROJ_N;
        const float* dt_wi    = dt_w    + (size_t)i * DT_RANK * D_INNER;
        const float* dt_bi    = dt_b    + (size_t)i * D_INNER;
        const float* A_logi   = A_log   + (size_t)i * D_INNER * D_STATE;
        const float* D_parami = D_param + (size_t)i * D_INNER;
        const float* out_wi   = out_w   + (size_t)i * D_INNER * D_MODEL;
        const float* norm_wi  = norm_w  + (size_t)i * D_MODEL;

        // x = rmsnorm(h)
        rmsnorm_k<<<M_TOK, blk, 0, stream>>>(h, norm_wi, x);
        // xz = x @ in_w[i]
        gemm64<0><<<dim3(M_TOK / 64, (2 * D_INNER) / 64), blk, 0, stream>>>(
            x, D_MODEL, in_wi, 2 * D_INNER, xz, 2 * D_INNER, nullptr,
            2 * D_INNER, D_MODEL);
        // xc = silu(conv(xi) + conv_b)
        conv_silu_k<<<(M_TOK * D_INNER) / 256, blk, 0, stream>>>(
            xz, conv_wi, conv_bi, xc);
        // xdbl = xc @ xproj_w[i]
        gemm64<0><<<dim3(M_TOK / 64, (XPROJ_N + 63) / 64), blk, 0, stream>>>(
            xc, D_INNER, xproj_wi, XPROJ_N, xdbl, XPROJ_N, nullptr,
            XPROJ_N, D_INNER);
        // delta = softplus(xdbl[:, :48] @ dt_w[i] + dt_b[i])
        gemm64<2><<<dim3(M_TOK / 64, D_INNER / 64), blk, 0, stream>>>(
            xdbl, XPROJ_N, dt_wi, D_INNER, delta, D_INNER, dt_bi,
            D_INNER, DT_RANK);
        // y = scan(...) fused with (+u*D) * silu(res)
        scan_k<<<BATCH * (D_INNER / 256), blk, 0, stream>>>(
            delta, xc, xdbl, xz, A_logi, D_parami, y);
        // h += y @ out_w[i]
        gemm64<3><<<dim3(M_TOK / 64, D_MODEL / 64), blk, 0, stream>>>(
            y, D_INNER, out_wi, D_MODEL, h, D_MODEL, nullptr,
            D_MODEL, D_INNER);
    }

    // out = rmsnorm(h, normf_w)
    rmsnorm_k<<<M_TOK, blk, 0, stream>>>(h, normf_w, (float*)d_out);
}

// Round 2
// 5026.057 us; speedup vs baseline: 1.4174x; 1.4174x over previous
//
#include <hip/hip_runtime.h>
#include <cmath>

#define IMG_DIM 512
#define D_MODEL 768
#define N_LAYER 12
#define D_INNER 1536
#define D_STATE 16
#define D_CONV 4
#define DT_RANK 48
#define BATCH 4
#define SEQ 256
#define M_TOK (BATCH * SEQ)               // 1024 token rows
#define XPROJ_N (DT_RANK + 2 * D_STATE)   // 80

__device__ __forceinline__ float softplus_f(float v) {
    return v > 20.f ? v : log1pf(expf(v));
}

// ---------------------------------------------------------------------------
// Generic fp32 GEMM: C[M,N] = A[M,K] @ B[K,N] (+ epilogue)
// 64x64 tile, BK=16, 256 threads, 4x4 accum per thread.
// EPI: 0 = store, 1 = bias+relu, 2 = bias+softplus, 3 = accumulate into C
// ---------------------------------------------------------------------------
template <int EPI>
__global__ __launch_bounds__(256) void gemm64(
    const float* __restrict__ A, int lda,
    const float* __restrict__ B, int ldb,
    float* __restrict__ C, int ldc,
    const float* __restrict__ bias,
    int N, int K)
{
    __shared__ float As[16][64];
    __shared__ float Bs[16][64];
    const int tid = threadIdx.x;
    const int tx = tid & 15, ty = tid >> 4;
    const int rowBase = blockIdx.x * 64;
    const int colBase = blockIdx.y * 64;
    const int ar = tid >> 2, ak = (tid & 3) * 4;   // A-tile loader coords
    const int br = tid >> 4, bc = (tid & 15) * 4;  // B-tile loader coords

    float acc[4][4] = {};

    for (int k0 = 0; k0 < K; k0 += 16) {
        float4 av = *(const float4*)&A[(size_t)(rowBase + ar) * lda + k0 + ak];
        As[ak + 0][ar] = av.x;
        As[ak + 1][ar] = av.y;
        As[ak + 2][ar] = av.z;
        As[ak + 3][ar] = av.w;

        int gcol = colBase + bc;
        float4 bv;
        if (gcol + 3 < N) {
            bv = *(const float4*)&B[(size_t)(k0 + br) * ldb + gcol];
        } else {
            const float* bp = &B[(size_t)(k0 + br) * ldb];
            bv.x = (gcol + 0 < N) ? bp[gcol + 0] : 0.f;
            bv.y = (gcol + 1 < N) ? bp[gcol + 1] : 0.f;
            bv.z = (gcol + 2 < N) ? bp[gcol + 2] : 0.f;
            bv.w = (gcol + 3 < N) ? bp[gcol + 3] : 0.f;
        }
        *(float4*)&Bs[br][bc] = bv;

        __syncthreads();
        #pragma unroll
        for (int k = 0; k < 16; ++k) {
            float4 a = *(const float4*)&As[k][ty * 4];
            float4 b = *(const float4*)&Bs[k][tx * 4];
            float am[4] = {a.x, a.y, a.z, a.w};
            float bm[4] = {b.x, b.y, b.z, b.w};
            #pragma unroll
            for (int i = 0; i < 4; ++i)
                #pragma unroll
                for (int j = 0; j < 4; ++j)
                    acc[i][j] = fmaf(am[i], bm[j], acc[i][j]);
        }
        __syncthreads();
    }

    #pragma unroll
    for (int i = 0; i < 4; ++i) {
        int r = rowBase + ty * 4 + i;
        #pragma unroll
        for (int j = 0; j < 4; ++j) {
            int c = colBase + tx * 4 + j;
            if (c >= N) continue;
            float v = acc[i][j];
            float* dst = &C[(size_t)r * ldc + c];
            if (EPI == 0) {
                *dst = v;
            } else if (EPI == 1) {
                v += bias[c];
                *dst = v > 0.f ? v : 0.f;
            } else if (EPI == 2) {
                v += bias[c];
                *dst = softplus_f(v);
            } else {
                *dst += v;
            }
        }
    }
}

// ---------------------------------------------------------------------------
// RMSNorm: one block per token row (768 cols), 256 threads x 3 elements
// ---------------------------------------------------------------------------
__global__ __launch_bounds__(256) void rmsnorm_k(
    const float* __restrict__ x, const float* __restrict__ w,
    float* __restrict__ o)
{
    const int row = blockIdx.x;
    const float* xr = x + (size_t)row * D_MODEL;
    float v[3];
    float s = 0.f;
    #pragma unroll
    for (int i = 0; i < 3; ++i) {
        v[i] = xr[threadIdx.x + i * 256];
        s = fmaf(v[i], v[i], s);
    }
    #pragma unroll
    for (int off = 32; off > 0; off >>= 1) s += __shfl_down(s, off);
    __shared__ float red[4];
    if ((threadIdx.x & 63) == 0) red[threadIdx.x >> 6] = s;
    __syncthreads();
    float tot = red[0] + red[1] + red[2] + red[3];
    float r = rsqrtf(tot * (1.f / D_MODEL) + 1e-5f);
    float* orow = o + (size_t)row * D_MODEL;
    #pragma unroll
    for (int i = 0; i < 3; ++i) {
        int c = threadIdx.x + i * 256;
        orow[c] = v[i] * r * w[c];
    }
}

// ---------------------------------------------------------------------------
// Causal depthwise conv (width 4, left pad 3) + bias + silu
// ---------------------------------------------------------------------------
__global__ __launch_bounds__(256) void conv_silu_k(
    const float* __restrict__ xz, const float* __restrict__ cw,
    const float* __restrict__ cb, float* __restrict__ xc)
{
    int idx = blockIdx.x * 256 + threadIdx.x;   // over 1024*1536
    int d = idx % D_INNER;
    int bt = idx / D_INNER;
    int t = bt & (SEQ - 1);
    int b = bt >> 8;
    float acc = cb[d];
    #pragma unroll
    for (int k = 0; k < 4; ++k) {
        int tt = t - 3 + k;
        if (tt >= 0)
            acc = fmaf(xz[(size_t)(b * SEQ + tt) * (2 * D_INNER) + d], cw[d * 4 + k], acc);
    }
    float sig = 1.f / (1.f + expf(-acc));
    xc[idx] = acc * sig;
}

// ---------------------------------------------------------------------------
// Selective scan, state-parallel: one thread per (b, d, n).
// 16 lanes (one n-group) share a d; per-step y-reduce = 4-step shfl_xor
// butterfly within the 16-lane group. Prefetch t+1 loads over the exp chain.
// Fused epilogue: y = (scan_y + u*D) * silu(res)
// ---------------------------------------------------------------------------
__global__ __launch_bounds__(256) void scan_k(
    const float* __restrict__ delta,  // [1024][1536]
    const float* __restrict__ xc,     // [1024][1536] (u)
    const float* __restrict__ xdbl,   // [1024][80]  (B at 48, C at 64)
    const float* __restrict__ xz,     // [1024][3072] (res at col 1536+d)
    const float* __restrict__ A_log,  // [1536][16]
    const float* __restrict__ D_param,// [1536]
    float* __restrict__ y)            // [1024][1536]
{
    const int tid = threadIdx.x;
    const int n  = tid & 15;           // state index
    const int dd = tid >> 4;           // 0..15 within block
    const int blocksPerB = D_INNER / 16;          // 96
    const int b = blockIdx.x / blocksPerB;
    const int d = (blockIdx.x % blocksPerB) * 16 + dd;

    const float A  = -expf(A_log[(size_t)d * D_STATE + n]);
    const float Dp = D_param[d];
    float h = 0.f;

    const float* dp = delta + (size_t)b * SEQ * D_INNER + d;
    const float* up = xc    + (size_t)b * SEQ * D_INNER + d;
    const float* rp = xz    + (size_t)b * SEQ * 2 * D_INNER + D_INNER + d;
    const float* xp = xdbl  + (size_t)b * SEQ * XPROJ_N + DT_RANK + n;
    float*       yp = y     + (size_t)b * SEQ * D_INNER + d;

    float dv = dp[0];
    float u  = up[0];
    float r  = rp[0];
    float Bv = xp[0];
    float Cv = xp[D_STATE];

    for (int t = 0; t < SEQ; ++t) {
        // prefetch t+1 (independent of the recurrence chain)
        float dv2 = 0.f, u2 = 0.f, r2 = 0.f, Bv2 = 0.f, Cv2 = 0.f;
        if (t + 1 < SEQ) {
            dv2 = dp[(size_t)(t + 1) * D_INNER];
            u2  = up[(size_t)(t + 1) * D_INNER];
            r2  = rp[(size_t)(t + 1) * 2 * D_INNER];
            Bv2 = xp[(size_t)(t + 1) * XPROJ_N];
            Cv2 = xp[(size_t)(t + 1) * XPROJ_N + D_STATE];
        }
        float dA = expf(dv * A);
        h = fmaf(dA, h, dv * u * Bv);
        float pv = h * Cv;
        pv += __shfl_xor(pv, 1);
        pv += __shfl_xor(pv, 2);
        pv += __shfl_xor(pv, 4);
        pv += __shfl_xor(pv, 8);
        float sr = r / (1.f + expf(-r));
        float out = (pv + u * Dp) * sr;
        if (n == 0) yp[(size_t)t * D_INNER] = out;
        dv = dv2; u = u2; r = r2; Bv = Bv2; Cv = Cv2;
    }
}

// ---------------------------------------------------------------------------
// Launch
// ---------------------------------------------------------------------------
extern "C" void kernel_launch(void* const* d_in, const int* in_sizes, int n_in,
                              void* d_out, int out_size, void* d_ws, size_t ws_size,
                              hipStream_t stream)
{
    const float* frames  = (const float*)d_in[0];
    const float* fproj_w = (const float*)d_in[1];
    const float* fproj_b = (const float*)d_in[2];
    const float* norm_w  = (const float*)d_in[3];
    const float* in_w    = (const float*)d_in[4];
    const float* conv_w  = (const float*)d_in[5];
    const float* conv_b  = (const float*)d_in[6];
    const float* xproj_w = (const float*)d_in[7];
    const float* dt_w    = (const float*)d_in[8];
    const float* dt_b    = (const float*)d_in[9];
    const float* A_log   = (const float*)d_in[10];
    const float* D_param = (const float*)d_in[11];
    const float* out_w   = (const float*)d_in[12];
    const float* normf_w = (const float*)d_in[13];

    // workspace layout (floats); total ~9.4M floats (~38 MB)
    float* ws = (float*)d_ws;
    float* h     = ws;                          // 1024*768
    float* x     = h + M_TOK * D_MODEL;         // 1024*768
    float* xz    = x + M_TOK * D_MODEL;         // 1024*3072
    float* xc    = xz + M_TOK * 2 * D_INNER;    // 1024*1536
    float* xdbl  = xc + M_TOK * D_INNER;        // 1024*80
    float* delta = xdbl + M_TOK * XPROJ_N;      // 1024*1536
    float* y     = delta + M_TOK * D_INNER;     // 1024*1536

    dim3 blk(256);

    // h = relu(frames @ fproj_w + fproj_b)
    gemm64<1><<<dim3(M_TOK / 64, D_MODEL / 64), blk, 0, stream>>>(
        frames, IMG_DIM, fproj_w, D_MODEL, h, D_MODEL, fproj_b, D_MODEL, IMG_DIM);

    for (int i = 0; i < N_LAYER; ++i) {
        const float* in_wi    = in_w    + (size_t)i * D_MODEL * 2 * D_INNER;
        const float* conv_wi  = conv_w  + (size_t)i * D_INNER * D_CONV;
        const float* conv_bi  = conv_b  + (size_t)i * D_INNER;
        const float* xproj_wi = xproj_w + (size_t)i * D_INNER * XPROJ_N;
        const float* dt_wi    = dt_w    + (size_t)i * DT_RANK * D_INNER;
        const float* dt_bi    = dt_b    + (size_t)i * D_INNER;
        const float* A_logi   = A_log   + (size_t)i * D_INNER * D_STATE;
        const float* D_parami = D_param + (size_t)i * D_INNER;
        const float* out_wi   = out_w   + (size_t)i * D_INNER * D_MODEL;
        const float* norm_wi  = norm_w  + (size_t)i * D_MODEL;

        // x = rmsnorm(h)
        rmsnorm_k<<<M_TOK, blk, 0, stream>>>(h, norm_wi, x);
        // xz = x @ in_w[i]
        gemm64<0><<<dim3(M_TOK / 64, (2 * D_INNER) / 64), blk, 0, stream>>>(
            x, D_MODEL, in_wi, 2 * D_INNER, xz, 2 * D_INNER, nullptr,
            2 * D_INNER, D_MODEL);
        // xc = silu(conv(xi) + conv_b)
        conv_silu_k<<<(M_TOK * D_INNER) / 256, blk, 0, stream>>>(
            xz, conv_wi, conv_bi, xc);
        // xdbl = xc @ xproj_w[i]
        gemm64<0><<<dim3(M_TOK / 64, (XPROJ_N + 63) / 64), blk, 0, stream>>>(
            xc, D_INNER, xproj_wi, XPROJ_N, xdbl, XPROJ_N, nullptr,
            XPROJ_N, D_INNER);
        // delta = softplus(xdbl[:, :48] @ dt_w[i] + dt_b[i])
        gemm64<2><<<dim3(M_TOK / 64, D_INNER / 64), blk, 0, stream>>>(
            xdbl, XPROJ_N, dt_wi, D_INNER, delta, D_INNER, dt_bi,
            D_INNER, DT_RANK);
        // y = scan(...) fused with (+u*D) * silu(res)  — state-parallel
        scan_k<<<BATCH * (D_INNER / 16), blk, 0, stream>>>(
            delta, xc, xdbl, xz, A_logi, D_parami, y);
        // h += y @ out_w[i]
        gemm64<3><<<dim3(M_TOK / 64, D_MODEL / 64), blk, 0, stream>>>(
            y, D_INNER, out_wi, D_MODEL, h, D_MODEL, nullptr,
            D_MODEL, D_INNER);
    }

    // out = rmsnorm(h, normf_w)
    rmsnorm_k<<<M_TOK, blk, 0, stream>>>(h, normf_w, (float*)d_out);
}

// Round 3
// 3234.525 us; speedup vs baseline: 2.2025x; 1.5539x over previous
//
#include <hip/hip_runtime.h>
#include <hip/hip_bf16.h>
#include <cmath>

#define IMG_DIM 512
#define D_MODEL 768
#define N_LAYER 12
#define D_INNER 1536
#define D_STATE 16
#define D_CONV 4
#define DT_RANK 48
#define BATCH 4
#define SEQ 256
#define M_TOK (BATCH * SEQ)               // 1024 token rows
#define XPROJ_N (DT_RANK + 2 * D_STATE)   // 80

typedef __attribute__((ext_vector_type(8))) short bf16x8;
typedef __attribute__((ext_vector_type(4))) float f32x4;

__device__ __forceinline__ float softplus_f(float v) {
    return v > 20.f ? v : log1pf(expf(v));
}

// ---------------------------------------------------------------------------
// fp32 GEMM (kept for fproj / xproj / dt): 64x64 tile, BK=16, 4x4/thread
// EPI: 0 = store, 1 = bias+relu, 2 = bias+softplus
// ---------------------------------------------------------------------------
template <int EPI>
__global__ __launch_bounds__(256) void gemm64(
    const float* __restrict__ A, int lda,
    const float* __restrict__ B, int ldb,
    float* __restrict__ C, int ldc,
    const float* __restrict__ bias,
    int N, int K)
{
    __shared__ float As[16][64];
    __shared__ float Bs[16][64];
    const int tid = threadIdx.x;
    const int tx = tid & 15, ty = tid >> 4;
    const int rowBase = blockIdx.x * 64;
    const int colBase = blockIdx.y * 64;
    const int ar = tid >> 2, ak = (tid & 3) * 4;
    const int br = tid >> 4, bc = (tid & 15) * 4;

    float acc[4][4] = {};

    for (int k0 = 0; k0 < K; k0 += 16) {
        float4 av = *(const float4*)&A[(size_t)(rowBase + ar) * lda + k0 + ak];
        As[ak + 0][ar] = av.x;
        As[ak + 1][ar] = av.y;
        As[ak + 2][ar] = av.z;
        As[ak + 3][ar] = av.w;

        int gcol = colBase + bc;
        float4 bv;
        if (gcol + 3 < N) {
            bv = *(const float4*)&B[(size_t)(k0 + br) * ldb + gcol];
        } else {
            const float* bp = &B[(size_t)(k0 + br) * ldb];
            bv.x = (gcol + 0 < N) ? bp[gcol + 0] : 0.f;
            bv.y = (gcol + 1 < N) ? bp[gcol + 1] : 0.f;
            bv.z = (gcol + 2 < N) ? bp[gcol + 2] : 0.f;
            bv.w = (gcol + 3 < N) ? bp[gcol + 3] : 0.f;
        }
        *(float4*)&Bs[br][bc] = bv;

        __syncthreads();
        #pragma unroll
        for (int k = 0; k < 16; ++k) {
            float4 a = *(const float4*)&As[k][ty * 4];
            float4 b = *(const float4*)&Bs[k][tx * 4];
            float am[4] = {a.x, a.y, a.z, a.w};
            float bm[4] = {b.x, b.y, b.z, b.w};
            #pragma unroll
            for (int i = 0; i < 4; ++i)
                #pragma unroll
                for (int j = 0; j < 4; ++j)
                    acc[i][j] = fmaf(am[i], bm[j], acc[i][j]);
        }
        __syncthreads();
    }

    #pragma unroll
    for (int i = 0; i < 4; ++i) {
        int r = rowBase + ty * 4 + i;
        #pragma unroll
        for (int j = 0; j < 4; ++j) {
            int c = colBase + tx * 4 + j;
            if (c >= N) continue;
            float v = acc[i][j];
            float* dst = &C[(size_t)r * ldc + c];
            if (EPI == 0) {
                *dst = v;
            } else if (EPI == 1) {
                v += bias[c];
                *dst = v > 0.f ? v : 0.f;
            } else {
                v += bias[c];
                *dst = softplus_f(v);
            }
        }
    }
}

// ---------------------------------------------------------------------------
// Weight transpose + fp32->bf16 convert: W[K][N] -> WT[N][K]
// ---------------------------------------------------------------------------
__global__ __launch_bounds__(256) void wcvt_t_k(
    const float* __restrict__ W, __hip_bfloat16* __restrict__ WT,
    int K, int N)
{
    __shared__ float tile[32][33];
    const int tx = threadIdx.x & 31;
    const int ty4 = (threadIdx.x >> 5) * 4;
    const int n0 = blockIdx.x * 32, k0 = blockIdx.y * 32;
    #pragma unroll
    for (int r = 0; r < 4; ++r)
        tile[ty4 + r][tx] = W[(size_t)(k0 + ty4 + r) * N + n0 + tx];
    __syncthreads();
    #pragma unroll
    for (int r = 0; r < 4; ++r)
        WT[(size_t)(n0 + ty4 + r) * K + k0 + tx] =
            __float2bfloat16(tile[tx][ty4 + r]);
}

// ---------------------------------------------------------------------------
// bf16 MFMA GEMM: C[M,N](f32) = A[M,K](bf16) @ BT[N,K](bf16)^T
// 64x64 block tile, BK=64, 256 thr (4 waves 2x2, 32x32 each),
// XOR-swizzled LDS, reg-staged double buffer, 1 barrier/iter.
// EPI: 0 = store, 3 = accumulate
// ---------------------------------------------------------------------------
template <int EPI>
__global__ __launch_bounds__(256) void gemm_bf16(
    const __hip_bfloat16* __restrict__ A,
    const __hip_bfloat16* __restrict__ BT,
    float* __restrict__ C, int ldc, int K)
{
    __shared__ __align__(16) char lds[2][16384];   // [buf][A 8K | B 8K]
    const int tid = threadIdx.x;
    const int lane = tid & 63;
    const int wid = tid >> 6;
    const int wr = wid >> 1, wc = wid & 1;
    const size_t rowBase = blockIdx.x * 64;
    const size_t colBase = blockIdx.y * 64;

    // staging: slot s in [0,512): row = s>>3, logical colbyte = (s&7)*16
    const int r0 = tid >> 3;
    const int cb0 = (tid & 7) * 16;
    const int wOffA = r0 * 128 + (cb0 ^ ((r0 & 7) << 4));  // phys, buf-rel
    const char* gA = (const char*)(A + rowBase * K);
    const char* gB = (const char*)(BT + colBase * K);
    const size_t rowByteOff = (size_t)r0 * K * 2 + cb0;

    // frag read coords
    const int lrow = lane & 15;
    const int kg = (lane >> 4) * 16;
    const int swz = (lane & 7) << 4;

    f32x4 acc[2][2] = {};

    const int nt = K >> 6;
    float4 ra0, ra1, rb0, rb1;

    // prologue: load + write tile 0
    ra0 = *(const float4*)(gA + rowByteOff);
    ra1 = *(const float4*)(gA + rowByteOff + (size_t)32 * K * 2);
    rb0 = *(const float4*)(gB + rowByteOff);
    rb1 = *(const float4*)(gB + rowByteOff + (size_t)32 * K * 2);
    *(float4*)(&lds[0][wOffA])        = ra0;
    *(float4*)(&lds[0][wOffA + 4096]) = ra1;
    *(float4*)(&lds[0][wOffA + 8192]) = rb0;
    *(float4*)(&lds[0][wOffA + 12288])= rb1;
    __syncthreads();

    for (int t = 0; t < nt; ++t) {
        const int cur = t & 1;
        if (t + 1 < nt) {
            size_t off = rowByteOff + (size_t)(t + 1) * 128;
            ra0 = *(const float4*)(gA + off);
            ra1 = *(const float4*)(gA + off + (size_t)32 * K * 2);
            rb0 = *(const float4*)(gB + off);
            rb1 = *(const float4*)(gB + off + (size_t)32 * K * 2);
        }
        // compute on buf cur
        #pragma unroll
        for (int kk = 0; kk < 2; ++kk) {
            const int col = (kk * 64 + kg) ^ swz;
            bf16x8 a0 = *(const bf16x8*)(&lds[cur][(wr * 32 +      lrow) * 128 + col]);
            bf16x8 a1 = *(const bf16x8*)(&lds[cur][(wr * 32 + 16 + lrow) * 128 + col]);
            bf16x8 b0 = *(const bf16x8*)(&lds[cur][8192 + (wc * 32 +      lrow) * 128 + col]);
            bf16x8 b1 = *(const bf16x8*)(&lds[cur][8192 + (wc * 32 + 16 + lrow) * 128 + col]);
            acc[0][0] = __builtin_amdgcn_mfma_f32_16x16x32_bf16(a0, b0, acc[0][0], 0, 0, 0);
            acc[0][1] = __builtin_amdgcn_mfma_f32_16x16x32_bf16(a0, b1, acc[0][1], 0, 0, 0);
            acc[1][0] = __builtin_amdgcn_mfma_f32_16x16x32_bf16(a1, b0, acc[1][0], 0, 0, 0);
            acc[1][1] = __builtin_amdgcn_mfma_f32_16x16x32_bf16(a1, b1, acc[1][1], 0, 0, 0);
        }
        if (t + 1 < nt) {
            const int nxt = cur ^ 1;
            *(float4*)(&lds[nxt][wOffA])        = ra0;
            *(float4*)(&lds[nxt][wOffA + 4096]) = ra1;
            *(float4*)(&lds[nxt][wOffA + 8192]) = rb0;
            *(float4*)(&lds[nxt][wOffA + 12288])= rb1;
        }
        __syncthreads();
    }

    // epilogue: C/D layout col = lane&15, row = (lane>>4)*4 + reg
    const int mBase = (int)rowBase + wr * 32 + (lane >> 4) * 4;
    const int nBase = (int)colBase + wc * 32 + (lane & 15);
    #pragma unroll
    for (int i = 0; i < 2; ++i)
        #pragma unroll
        for (int j = 0; j < 2; ++j)
            #pragma unroll
            for (int rg = 0; rg < 4; ++rg) {
                size_t idx = (size_t)(mBase + i * 16 + rg) * ldc + nBase + j * 16;
                if (EPI == 3) C[idx] += acc[i][j][rg];
                else          C[idx]  = acc[i][j][rg];
            }
}

// ---------------------------------------------------------------------------
// RMSNorm: one block per token row; templated output type (f32 or bf16)
// ---------------------------------------------------------------------------
template <typename OT>
__global__ __launch_bounds__(256) void rmsnorm_k(
    const float* __restrict__ x, const float* __restrict__ w,
    OT* __restrict__ o)
{
    const int row = blockIdx.x;
    const float* xr = x + (size_t)row * D_MODEL;
    float v[3];
    float s = 0.f;
    #pragma unroll
    for (int i = 0; i < 3; ++i) {
        v[i] = xr[threadIdx.x + i * 256];
        s = fmaf(v[i], v[i], s);
    }
    #pragma unroll
    for (int off = 32; off > 0; off >>= 1) s += __shfl_down(s, off);
    __shared__ float red[4];
    if ((threadIdx.x & 63) == 0) red[threadIdx.x >> 6] = s;
    __syncthreads();
    float tot = red[0] + red[1] + red[2] + red[3];
    float r = rsqrtf(tot * (1.f / D_MODEL) + 1e-5f);
    OT* orow = o + (size_t)row * D_MODEL;
    #pragma unroll
    for (int i = 0; i < 3; ++i) {
        int c = threadIdx.x + i * 256;
        orow[c] = (OT)(v[i] * r * w[c]);
    }
}

// ---------------------------------------------------------------------------
// Causal depthwise conv (width 4) + bias + silu
// ---------------------------------------------------------------------------
__global__ __launch_bounds__(256) void conv_silu_k(
    const float* __restrict__ xz, const float* __restrict__ cw,
    const float* __restrict__ cb, float* __restrict__ xc)
{
    int idx = blockIdx.x * 256 + threadIdx.x;
    int d = idx % D_INNER;
    int bt = idx / D_INNER;
    int t = bt & (SEQ - 1);
    int b = bt >> 8;
    float acc = cb[d];
    #pragma unroll
    for (int k = 0; k < 4; ++k) {
        int tt = t - 3 + k;
        if (tt >= 0)
            acc = fmaf(xz[(size_t)(b * SEQ + tt) * (2 * D_INNER) + d], cw[d * 4 + k], acc);
    }
    float sig = 1.f / (1.f + expf(-acc));
    xc[idx] = acc * sig;
}

// ---------------------------------------------------------------------------
// Selective scan, state-parallel (thread per (b,d,n)); y written as bf16
// ---------------------------------------------------------------------------
__global__ __launch_bounds__(256) void scan_k(
    const float* __restrict__ delta,
    const float* __restrict__ xc,
    const float* __restrict__ xdbl,
    const float* __restrict__ xz,
    const float* __restrict__ A_log,
    const float* __restrict__ D_param,
    __hip_bfloat16* __restrict__ y)
{
    const int tid = threadIdx.x;
    const int n  = tid & 15;
    const int dd = tid >> 4;
    const int blocksPerB = D_INNER / 16;          // 96
    const int b = blockIdx.x / blocksPerB;
    const int d = (blockIdx.x % blocksPerB) * 16 + dd;

    const float A  = -expf(A_log[(size_t)d * D_STATE + n]);
    const float Dp = D_param[d];
    float h = 0.f;

    const float* dp = delta + (size_t)b * SEQ * D_INNER + d;
    const float* up = xc    + (size_t)b * SEQ * D_INNER + d;
    const float* rp = xz    + (size_t)b * SEQ * 2 * D_INNER + D_INNER + d;
    const float* xp = xdbl  + (size_t)b * SEQ * XPROJ_N + DT_RANK + n;
    __hip_bfloat16* yp = y  + (size_t)b * SEQ * D_INNER + d;

    float dv = dp[0];
    float u  = up[0];
    float r  = rp[0];
    float Bv = xp[0];
    float Cv = xp[D_STATE];

    for (int t = 0; t < SEQ; ++t) {
        float dv2 = 0.f, u2 = 0.f, r2 = 0.f, Bv2 = 0.f, Cv2 = 0.f;
        if (t + 1 < SEQ) {
            dv2 = dp[(size_t)(t + 1) * D_INNER];
            u2  = up[(size_t)(t + 1) * D_INNER];
            r2  = rp[(size_t)(t + 1) * 2 * D_INNER];
            Bv2 = xp[(size_t)(t + 1) * XPROJ_N];
            Cv2 = xp[(size_t)(t + 1) * XPROJ_N + D_STATE];
        }
        float dA = expf(dv * A);
        h = fmaf(dA, h, dv * u * Bv);
        float pv = h * Cv;
        pv += __shfl_xor(pv, 1);
        pv += __shfl_xor(pv, 2);
        pv += __shfl_xor(pv, 4);
        pv += __shfl_xor(pv, 8);
        float sr = r / (1.f + expf(-r));
        float out = (pv + u * Dp) * sr;
        if (n == 0) yp[(size_t)t * D_INNER] = __float2bfloat16(out);
        dv = dv2; u = u2; r = r2; Bv = Bv2; Cv = Cv2;
    }
}

// ---------------------------------------------------------------------------
// Launch
// ---------------------------------------------------------------------------
extern "C" void kernel_launch(void* const* d_in, const int* in_sizes, int n_in,
                              void* d_out, int out_size, void* d_ws, size_t ws_size,
                              hipStream_t stream)
{
    const float* frames  = (const float*)d_in[0];
    const float* fproj_w = (const float*)d_in[1];
    const float* fproj_b = (const float*)d_in[2];
    const float* norm_w  = (const float*)d_in[3];
    const float* in_w    = (const float*)d_in[4];
    const float* conv_w  = (const float*)d_in[5];
    const float* conv_b  = (const float*)d_in[6];
    const float* xproj_w = (const float*)d_in[7];
    const float* dt_w    = (const float*)d_in[8];
    const float* dt_b    = (const float*)d_in[9];
    const float* A_log   = (const float*)d_in[10];
    const float* D_param = (const float*)d_in[11];
    const float* out_w   = (const float*)d_in[12];
    const float* normf_w = (const float*)d_in[13];

    // workspace layout (bytes, all 256-aligned)
    char* ws = (char*)d_ws;
    float* h      = (float*)ws;                         ws += (size_t)M_TOK * D_MODEL * 4;        // 3.0 MB
    float* xz     = (float*)ws;                         ws += (size_t)M_TOK * 2 * D_INNER * 4;    // 12.0 MB
    float* xc     = (float*)ws;                         ws += (size_t)M_TOK * D_INNER * 4;        // 6.0 MB
    float* xdbl   = (float*)ws;                         ws += (size_t)M_TOK * XPROJ_N * 4;        // 0.31 MB
    float* delta  = (float*)ws;                         ws += (size_t)M_TOK * D_INNER * 4;        // 6.0 MB
    __hip_bfloat16* x_bf   = (__hip_bfloat16*)ws;       ws += (size_t)M_TOK * D_MODEL * 2;        // 1.5 MB
    __hip_bfloat16* y_bf   = (__hip_bfloat16*)ws;       ws += (size_t)M_TOK * D_INNER * 2;        // 3.0 MB
    __hip_bfloat16* in_wT  = (__hip_bfloat16*)ws;       ws += (size_t)(2 * D_INNER) * D_MODEL * 2;// 4.5 MB
    __hip_bfloat16* out_wT = (__hip_bfloat16*)ws;       ws += (size_t)D_MODEL * D_INNER * 2;      // 2.25 MB

    dim3 blk(256);

    // h = relu(frames @ fproj_w + fproj_b)   (fp32)
    gemm64<1><<<dim3(M_TOK / 64, D_MODEL / 64), blk, 0, stream>>>(
        frames, IMG_DIM, fproj_w, D_MODEL, h, D_MODEL, fproj_b, D_MODEL, IMG_DIM);

    for (int i = 0; i < N_LAYER; ++i) {
        const float* in_wi    = in_w    + (size_t)i * D_MODEL * 2 * D_INNER;
        const float* conv_wi  = conv_w  + (size_t)i * D_INNER * D_CONV;
        const float* conv_bi  = conv_b  + (size_t)i * D_INNER;
        const float* xproj_wi = xproj_w + (size_t)i * D_INNER * XPROJ_N;
        const float* dt_wi    = dt_w    + (size_t)i * DT_RANK * D_INNER;
        const float* dt_bi    = dt_b    + (size_t)i * D_INNER;
        const float* A_logi   = A_log   + (size_t)i * D_INNER * D_STATE;
        const float* D_parami = D_param + (size_t)i * D_INNER;
        const float* out_wi   = out_w   + (size_t)i * D_INNER * D_MODEL;
        const float* norm_wi  = norm_w  + (size_t)i * D_MODEL;

        // x_bf = bf16(rmsnorm(h))
        rmsnorm_k<__hip_bfloat16><<<M_TOK, blk, 0, stream>>>(h, norm_wi, x_bf);
        // in_wT = bf16(in_w[i]^T)   [3072][768]
        wcvt_t_k<<<dim3(2 * D_INNER / 32, D_MODEL / 32), blk, 0, stream>>>(
            in_wi, in_wT, D_MODEL, 2 * D_INNER);
        // xz = x_bf @ in_w[i]   (bf16 MFMA, fp32 out)
        gemm_bf16<0><<<dim3(M_TOK / 64, (2 * D_INNER) / 64), blk, 0, stream>>>(
            x_bf, in_wT, xz, 2 * D_INNER, D_MODEL);
        // xc = silu(conv(xi) + conv_b)
        conv_silu_k<<<(M_TOK * D_INNER) / 256, blk, 0, stream>>>(
            xz, conv_wi, conv_bi, xc);
        // xdbl = xc @ xproj_w[i]   (fp32)
        gemm64<0><<<dim3(M_TOK / 64, (XPROJ_N + 63) / 64), blk, 0, stream>>>(
            xc, D_INNER, xproj_wi, XPROJ_N, xdbl, XPROJ_N, nullptr,
            XPROJ_N, D_INNER);
        // delta = softplus(xdbl[:, :48] @ dt_w[i] + dt_b[i])   (fp32)
        gemm64<2><<<dim3(M_TOK / 64, D_INNER / 64), blk, 0, stream>>>(
            xdbl, XPROJ_N, dt_wi, D_INNER, delta, D_INNER, dt_bi,
            D_INNER, DT_RANK);
        // y_bf = scan(...) fused epilogue
        scan_k<<<BATCH * (D_INNER / 16), blk, 0, stream>>>(
            delta, xc, xdbl, xz, A_logi, D_parami, y_bf);
        // out_wT = bf16(out_w[i]^T)   [768][1536]
        wcvt_t_k<<<dim3(D_MODEL / 32, D_INNER / 32), blk, 0, stream>>>(
            out_wi, out_wT, D_INNER, D_MODEL);
        // h += y_bf @ out_w[i]   (bf16 MFMA, accumulate)
        gemm_bf16<3><<<dim3(M_TOK / 64, D_MODEL / 64), blk, 0, stream>>>(
            y_bf, out_wT, h, D_MODEL, D_INNER);
    }

    // out = rmsnorm(h, normf_w)  (fp32)
    rmsnorm_k<float><<<M_TOK, blk, 0, stream>>>(h, normf_w, (float*)d_out);
}

// Round 4
// 2126.387 us; speedup vs baseline: 3.3502x; 1.5211x over previous
//
#include <hip/hip_runtime.h>
#include <hip/hip_bf16.h>
#include <cmath>

#define IMG_DIM 512
#define D_MODEL 768
#define N_LAYER 12
#define D_INNER 1536
#define D_STATE 16
#define D_CONV 4
#define DT_RANK 48
#define BATCH 4
#define SEQ 256
#define M_TOK (BATCH * SEQ)               // 1024 token rows
#define XPROJ_N (DT_RANK + 2 * D_STATE)   // 80
#define KSPLIT 8

typedef __attribute__((ext_vector_type(8))) short bf16x8;
typedef __attribute__((ext_vector_type(4))) float f32x4;

__device__ __forceinline__ float softplus_f(float v) {
    return v > 20.f ? v : log1pf(expf(v));
}

// ---------------------------------------------------------------------------
// Weight transpose + fp32->bf16 convert: W[K][N] -> WT[N][K]; N-guarded
// ---------------------------------------------------------------------------
__global__ __launch_bounds__(256) void wcvt_t_k(
    const float* __restrict__ W, __hip_bfloat16* __restrict__ WT,
    int K, int N)
{
    __shared__ float tile[32][33];
    const int tx = threadIdx.x & 31;
    const int ty4 = (threadIdx.x >> 5) * 4;
    const int n0 = blockIdx.x * 32, k0 = blockIdx.y * 32;
    #pragma unroll
    for (int r = 0; r < 4; ++r)
        tile[ty4 + r][tx] = (n0 + tx < N)
            ? W[(size_t)(k0 + ty4 + r) * N + n0 + tx] : 0.f;
    __syncthreads();
    #pragma unroll
    for (int r = 0; r < 4; ++r)
        if (n0 + ty4 + r < N)
            WT[(size_t)(n0 + ty4 + r) * K + k0 + tx] =
                __float2bfloat16(tile[tx][ty4 + r]);
}

// ---------------------------------------------------------------------------
// Flat fp32 -> bf16 convert
// ---------------------------------------------------------------------------
__global__ __launch_bounds__(256) void cvt_bf16_k(
    const float* __restrict__ in, __hip_bfloat16* __restrict__ out, int n)
{
    int i = blockIdx.x * 256 + threadIdx.x;
    if (i < n) out[i] = __float2bfloat16(in[i]);
}

// ---------------------------------------------------------------------------
// dt_w [48][1536] -> dt_wT [1536][64] bf16, zero-padded k 48..63
// ---------------------------------------------------------------------------
__global__ __launch_bounds__(256) void dtw_cvt_k(
    const float* __restrict__ dt_w, __hip_bfloat16* __restrict__ dtwT)
{
    int idx = blockIdx.x * 256 + threadIdx.x;   // over 1536*64
    int k = idx & 63, n = idx >> 6;
    dtwT[idx] = (k < DT_RANK)
        ? __float2bfloat16(dt_w[(size_t)k * D_INNER + n])
        : __hip_bfloat16(0.f);
}

// ---------------------------------------------------------------------------
// bf16 MFMA GEMM: C[M,N](f32) = A[M,K](bf16) @ BT[N,K](bf16)^T
// 64x64 tile, BK=64, 4 waves (2x2, 32x32 each), XOR-swizzled LDS,
// reg-staged double buffer. Requires K % 64 == 0, N % 64 == 0.
// EPI: 0 = store, 1 = bias+relu, 2 = bias+softplus, 3 = accumulate
// ---------------------------------------------------------------------------
template <int EPI>
__global__ __launch_bounds__(256) void gemm_bf16(
    const __hip_bfloat16* __restrict__ A,
    const __hip_bfloat16* __restrict__ BT,
    float* __restrict__ C, int ldc, int K,
    const float* __restrict__ bias)
{
    __shared__ __align__(16) char lds[2][16384];   // [buf][A 8K | B 8K]
    const int tid = threadIdx.x;
    const int lane = tid & 63;
    const int wid = tid >> 6;
    const int wr = wid >> 1, wc = wid & 1;
    const size_t rowBase = blockIdx.x * 64;
    const size_t colBase = blockIdx.y * 64;

    const int r0 = tid >> 3;
    const int cb0 = (tid & 7) * 16;
    const int wOffA = r0 * 128 + (cb0 ^ ((r0 & 7) << 4));
    const char* gA = (const char*)(A + rowBase * K);
    const char* gB = (const char*)(BT + colBase * K);
    const size_t rowByteOff = (size_t)r0 * K * 2 + cb0;

    const int lrow = lane & 15;
    const int kg = (lane >> 4) * 16;
    const int swz = (lane & 7) << 4;

    f32x4 acc[2][2] = {};

    const int nt = K >> 6;
    float4 ra0, ra1, rb0, rb1;

    ra0 = *(const float4*)(gA + rowByteOff);
    ra1 = *(const float4*)(gA + rowByteOff + (size_t)32 * K * 2);
    rb0 = *(const float4*)(gB + rowByteOff);
    rb1 = *(const float4*)(gB + rowByteOff + (size_t)32 * K * 2);
    *(float4*)(&lds[0][wOffA])        = ra0;
    *(float4*)(&lds[0][wOffA + 4096]) = ra1;
    *(float4*)(&lds[0][wOffA + 8192]) = rb0;
    *(float4*)(&lds[0][wOffA + 12288])= rb1;
    __syncthreads();

    for (int t = 0; t < nt; ++t) {
        const int cur = t & 1;
        if (t + 1 < nt) {
            size_t off = rowByteOff + (size_t)(t + 1) * 128;
            ra0 = *(const float4*)(gA + off);
            ra1 = *(const float4*)(gA + off + (size_t)32 * K * 2);
            rb0 = *(const float4*)(gB + off);
            rb1 = *(const float4*)(gB + off + (size_t)32 * K * 2);
        }
        #pragma unroll
        for (int kk = 0; kk < 2; ++kk) {
            const int col = (kk * 64 + kg) ^ swz;
            bf16x8 a0 = *(const bf16x8*)(&lds[cur][(wr * 32 +      lrow) * 128 + col]);
            bf16x8 a1 = *(const bf16x8*)(&lds[cur][(wr * 32 + 16 + lrow) * 128 + col]);
            bf16x8 b0 = *(const bf16x8*)(&lds[cur][8192 + (wc * 32 +      lrow) * 128 + col]);
            bf16x8 b1 = *(const bf16x8*)(&lds[cur][8192 + (wc * 32 + 16 + lrow) * 128 + col]);
            acc[0][0] = __builtin_amdgcn_mfma_f32_16x16x32_bf16(a0, b0, acc[0][0], 0, 0, 0);
            acc[0][1] = __builtin_amdgcn_mfma_f32_16x16x32_bf16(a0, b1, acc[0][1], 0, 0, 0);
            acc[1][0] = __builtin_amdgcn_mfma_f32_16x16x32_bf16(a1, b0, acc[1][0], 0, 0, 0);
            acc[1][1] = __builtin_amdgcn_mfma_f32_16x16x32_bf16(a1, b1, acc[1][1], 0, 0, 0);
        }
        if (t + 1 < nt) {
            const int nxt = cur ^ 1;
            *(float4*)(&lds[nxt][wOffA])        = ra0;
            *(float4*)(&lds[nxt][wOffA + 4096]) = ra1;
            *(float4*)(&lds[nxt][wOffA + 8192]) = rb0;
            *(float4*)(&lds[nxt][wOffA + 12288])= rb1;
        }
        __syncthreads();
    }

    const int mBase = (int)rowBase + wr * 32 + (lane >> 4) * 4;
    const int nBase = (int)colBase + wc * 32 + (lane & 15);
    #pragma unroll
    for (int i = 0; i < 2; ++i)
        #pragma unroll
        for (int j = 0; j < 2; ++j)
            #pragma unroll
            for (int rg = 0; rg < 4; ++rg) {
                int cc = nBase + j * 16;
                size_t idx = (size_t)(mBase + i * 16 + rg) * ldc + cc;
                float v = acc[i][j][rg];
                if (EPI == 0) {
                    C[idx] = v;
                } else if (EPI == 1) {
                    v += bias[cc];
                    C[idx] = v > 0.f ? v : 0.f;
                } else if (EPI == 2) {
                    v += bias[cc];
                    C[idx] = softplus_f(v);
                } else {
                    C[idx] += v;
                }
            }
}

// ---------------------------------------------------------------------------
// Skinny split-K MFMA GEMM for xproj: part[s][1024][80] =
//   xc_bf[1024][1536] @ xprojT[80][1536]^T  over K-slice s (no LDS).
// 4 waves x 16 rows; 5 column-frags cover N=80.
// ---------------------------------------------------------------------------
__global__ __launch_bounds__(256) void xproj_gemm_k(
    const __hip_bfloat16* __restrict__ xc_bf,
    const __hip_bfloat16* __restrict__ xprojT,
    float* __restrict__ part)
{
    const int lane = threadIdx.x & 63;
    const int w = threadIdx.x >> 6;
    const int m0 = blockIdx.x * 64 + w * 16;
    const int ks = blockIdx.y;
    const int KS = D_INNER / KSPLIT;          // 192
    const int k0 = ks * KS;

    const int arow = m0 + (lane & 15);
    const int kgrp = (lane >> 4) * 8;

    f32x4 acc[5] = {};
    const __hip_bfloat16* ap = xc_bf + (size_t)arow * D_INNER + kgrp;
    const __hip_bfloat16* bp = xprojT + (size_t)(lane & 15) * D_INNER + kgrp;

    for (int k = k0; k < k0 + KS; k += 32) {
        bf16x8 a = *(const bf16x8*)(ap + k);
        #pragma unroll
        for (int f = 0; f < 5; ++f) {
            bf16x8 b = *(const bf16x8*)(bp + (size_t)f * 16 * D_INNER + k);
            acc[f] = __builtin_amdgcn_mfma_f32_16x16x32_bf16(a, b, acc[f], 0, 0, 0);
        }
    }

    float* out = part + (size_t)ks * M_TOK * XPROJ_N;
    const int rowb = blockIdx.x * 64 + w * 16 + (lane >> 4) * 4;
    #pragma unroll
    for (int f = 0; f < 5; ++f)
        #pragma unroll
        for (int rg = 0; rg < 4; ++rg)
            out[(size_t)(rowb + rg) * XPROJ_N + f * 16 + (lane & 15)] = acc[f][rg];
}

// ---------------------------------------------------------------------------
// Reduce split-K partials -> xdbl fp32 [1024][80]; cols<48 also -> dtin bf16
// ---------------------------------------------------------------------------
__global__ __launch_bounds__(256) void xproj_reduce_k(
    const float* __restrict__ part, float* __restrict__ xdbl,
    __hip_bfloat16* __restrict__ dtin)
{
    int idx = blockIdx.x * 256 + threadIdx.x;   // < 1024*80
    float s = 0.f;
    #pragma unroll
    for (int p = 0; p < KSPLIT; ++p)
        s += part[(size_t)p * M_TOK * XPROJ_N + idx];
    xdbl[idx] = s;
    int col = idx % XPROJ_N;
    int row = idx / XPROJ_N;
    if (col < DT_RANK)
        dtin[(size_t)row * 64 + col] = __float2bfloat16(s);
}

// ---------------------------------------------------------------------------
// RMSNorm: one block per token row; templated output type
// ---------------------------------------------------------------------------
template <typename OT>
__global__ __launch_bounds__(256) void rmsnorm_k(
    const float* __restrict__ x, const float* __restrict__ w,
    OT* __restrict__ o)
{
    const int row = blockIdx.x;
    const float* xr = x + (size_t)row * D_MODEL;
    float v[3];
    float s = 0.f;
    #pragma unroll
    for (int i = 0; i < 3; ++i) {
        v[i] = xr[threadIdx.x + i * 256];
        s = fmaf(v[i], v[i], s);
    }
    #pragma unroll
    for (int off = 32; off > 0; off >>= 1) s += __shfl_down(s, off);
    __shared__ float red[4];
    if ((threadIdx.x & 63) == 0) red[threadIdx.x >> 6] = s;
    __syncthreads();
    float tot = red[0] + red[1] + red[2] + red[3];
    float r = rsqrtf(tot * (1.f / D_MODEL) + 1e-5f);
    OT* orow = o + (size_t)row * D_MODEL;
    #pragma unroll
    for (int i = 0; i < 3; ++i) {
        int c = threadIdx.x + i * 256;
        orow[c] = (OT)(v[i] * r * w[c]);
    }
}

// ---------------------------------------------------------------------------
// Causal depthwise conv (width 4) + bias + silu; fp32 + bf16 outputs
// ---------------------------------------------------------------------------
__global__ __launch_bounds__(256) void conv_silu_k(
    const float* __restrict__ xz, const float* __restrict__ cw,
    const float* __restrict__ cb, float* __restrict__ xc,
    __hip_bfloat16* __restrict__ xc_bf)
{
    int idx = blockIdx.x * 256 + threadIdx.x;
    int d = idx % D_INNER;
    int bt = idx / D_INNER;
    int t = bt & (SEQ - 1);
    int b = bt >> 8;
    float acc = cb[d];
    #pragma unroll
    for (int k = 0; k < 4; ++k) {
        int tt = t - 3 + k;
        if (tt >= 0)
            acc = fmaf(xz[(size_t)(b * SEQ + tt) * (2 * D_INNER) + d], cw[d * 4 + k], acc);
    }
    float sig = 1.f / (1.f + expf(-acc));
    float v = acc * sig;
    xc[idx] = v;
    xc_bf[idx] = __float2bfloat16(v);
}

// ---------------------------------------------------------------------------
// Selective scan, state-parallel (thread per (b,d,n)); y written as bf16
// ---------------------------------------------------------------------------
__global__ __launch_bounds__(256) void scan_k(
    const float* __restrict__ delta,
    const float* __restrict__ xc,
    const float* __restrict__ xdbl,
    const float* __restrict__ xz,
    const float* __restrict__ A_log,
    const float* __restrict__ D_param,
    __hip_bfloat16* __restrict__ y)
{
    const int tid = threadIdx.x;
    const int n  = tid & 15;
    const int dd = tid >> 4;
    const int blocksPerB = D_INNER / 16;          // 96
    const int b = blockIdx.x / blocksPerB;
    const int d = (blockIdx.x % blocksPerB) * 16 + dd;

    const float A  = -expf(A_log[(size_t)d * D_STATE + n]);
    const float Dp = D_param[d];
    float h = 0.f;

    const float* dp = delta + (size_t)b * SEQ * D_INNER + d;
    const float* up = xc    + (size_t)b * SEQ * D_INNER + d;
    const float* rp = xz    + (size_t)b * SEQ * 2 * D_INNER + D_INNER + d;
    const float* xp = xdbl  + (size_t)b * SEQ * XPROJ_N + DT_RANK + n;
    __hip_bfloat16* yp = y  + (size_t)b * SEQ * D_INNER + d;

    float dv = dp[0];
    float u  = up[0];
    float r  = rp[0];
    float Bv = xp[0];
    float Cv = xp[D_STATE];

    for (int t = 0; t < SEQ; ++t) {
        float dv2 = 0.f, u2 = 0.f, r2 = 0.f, Bv2 = 0.f, Cv2 = 0.f;
        if (t + 1 < SEQ) {
            dv2 = dp[(size_t)(t + 1) * D_INNER];
            u2  = up[(size_t)(t + 1) * D_INNER];
            r2  = rp[(size_t)(t + 1) * 2 * D_INNER];
            Bv2 = xp[(size_t)(t + 1) * XPROJ_N];
            Cv2 = xp[(size_t)(t + 1) * XPROJ_N + D_STATE];
        }
        float dA = expf(dv * A);
        h = fmaf(dA, h, dv * u * Bv);
        float pv = h * Cv;
        pv += __shfl_xor(pv, 1);
        pv += __shfl_xor(pv, 2);
        pv += __shfl_xor(pv, 4);
        pv += __shfl_xor(pv, 8);
        float sr = r / (1.f + expf(-r));
        float out = (pv + u * Dp) * sr;
        if (n == 0) yp[(size_t)t * D_INNER] = __float2bfloat16(out);
        dv = dv2; u = u2; r = r2; Bv = Bv2; Cv = Cv2;
    }
}

// ---------------------------------------------------------------------------
// Launch
// ---------------------------------------------------------------------------
extern "C" void kernel_launch(void* const* d_in, const int* in_sizes, int n_in,
                              void* d_out, int out_size, void* d_ws, size_t ws_size,
                              hipStream_t stream)
{
    const float* frames  = (const float*)d_in[0];
    const float* fproj_w = (const float*)d_in[1];
    const float* fproj_b = (const float*)d_in[2];
    const float* norm_w  = (const float*)d_in[3];
    const float* in_w    = (const float*)d_in[4];
    const float* conv_w  = (const float*)d_in[5];
    const float* conv_b  = (const float*)d_in[6];
    const float* xproj_w = (const float*)d_in[7];
    const float* dt_w    = (const float*)d_in[8];
    const float* dt_b    = (const float*)d_in[9];
    const float* A_log   = (const float*)d_in[10];
    const float* D_param = (const float*)d_in[11];
    const float* out_w   = (const float*)d_in[12];
    const float* normf_w = (const float*)d_in[13];

    // workspace layout
    char* ws = (char*)d_ws;
    float* h      = (float*)ws;                   ws += (size_t)M_TOK * D_MODEL * 4;
    float* xz     = (float*)ws;                   ws += (size_t)M_TOK * 2 * D_INNER * 4;
    float* xc     = (float*)ws;                   ws += (size_t)M_TOK * D_INNER * 4;
    float* xdbl   = (float*)ws;                   ws += (size_t)M_TOK * XPROJ_N * 4;
    float* delta  = (float*)ws;                   ws += (size_t)M_TOK * D_INNER * 4;
    float* part   = (float*)ws;                   ws += (size_t)KSPLIT * M_TOK * XPROJ_N * 4;
    __hip_bfloat16* x_bf   = (__hip_bfloat16*)ws; ws += (size_t)M_TOK * D_MODEL * 2;
    __hip_bfloat16* y_bf   = (__hip_bfloat16*)ws; ws += (size_t)M_TOK * D_INNER * 2;
    __hip_bfloat16* xc_bf  = (__hip_bfloat16*)ws; ws += (size_t)M_TOK * D_INNER * 2;
    __hip_bfloat16* dtin   = (__hip_bfloat16*)ws; ws += (size_t)M_TOK * 64 * 2;
    __hip_bfloat16* fr_bf  = (__hip_bfloat16*)ws; ws += (size_t)M_TOK * IMG_DIM * 2;
    __hip_bfloat16* fp_wT  = (__hip_bfloat16*)ws; ws += (size_t)D_MODEL * IMG_DIM * 2;
    __hip_bfloat16* in_wT  = (__hip_bfloat16*)ws; ws += (size_t)(2 * D_INNER) * D_MODEL * 2;
    __hip_bfloat16* out_wT = (__hip_bfloat16*)ws; ws += (size_t)D_MODEL * D_INNER * 2;
    __hip_bfloat16* xprojT = (__hip_bfloat16*)ws; ws += (size_t)XPROJ_N * D_INNER * 2;
    __hip_bfloat16* dt_wT  = (__hip_bfloat16*)ws; ws += (size_t)D_INNER * 64 * 2;

    dim3 blk(256);

    // zero dtin once per call (pad cols 48..63 must be 0)
    hipMemsetAsync(dtin, 0, (size_t)M_TOK * 64 * 2, stream);

    // h = relu(frames @ fproj_w + fproj_b)   (bf16 MFMA)
    cvt_bf16_k<<<(M_TOK * IMG_DIM) / 256, blk, 0, stream>>>(
        frames, fr_bf, M_TOK * IMG_DIM);
    wcvt_t_k<<<dim3(D_MODEL / 32, IMG_DIM / 32), blk, 0, stream>>>(
        fproj_w, fp_wT, IMG_DIM, D_MODEL);
    gemm_bf16<1><<<dim3(M_TOK / 64, D_MODEL / 64), blk, 0, stream>>>(
        fr_bf, fp_wT, h, D_MODEL, IMG_DIM, fproj_b);

    for (int i = 0; i < N_LAYER; ++i) {
        const float* in_wi    = in_w    + (size_t)i * D_MODEL * 2 * D_INNER;
        const float* conv_wi  = conv_w  + (size_t)i * D_INNER * D_CONV;
        const float* conv_bi  = conv_b  + (size_t)i * D_INNER;
        const float* xproj_wi = xproj_w + (size_t)i * D_INNER * XPROJ_N;
        const float* dt_wi    = dt_w    + (size_t)i * DT_RANK * D_INNER;
        const float* dt_bi    = dt_b    + (size_t)i * D_INNER;
        const float* A_logi   = A_log   + (size_t)i * D_INNER * D_STATE;
        const float* D_parami = D_param + (size_t)i * D_INNER;
        const float* out_wi   = out_w   + (size_t)i * D_INNER * D_MODEL;
        const float* norm_wi  = norm_w  + (size_t)i * D_MODEL;

        // x_bf = bf16(rmsnorm(h))
        rmsnorm_k<__hip_bfloat16><<<M_TOK, blk, 0, stream>>>(h, norm_wi, x_bf);
        // in_wT = bf16(in_w[i]^T)
        wcvt_t_k<<<dim3(2 * D_INNER / 32, D_MODEL / 32), blk, 0, stream>>>(
            in_wi, in_wT, D_MODEL, 2 * D_INNER);
        // xz = x_bf @ in_w[i]
        gemm_bf16<0><<<dim3(M_TOK / 64, (2 * D_INNER) / 64), blk, 0, stream>>>(
            x_bf, in_wT, xz, 2 * D_INNER, D_MODEL, nullptr);
        // xc = silu(conv(xi) + conv_b)  (+ bf16 copy)
        conv_silu_k<<<(M_TOK * D_INNER) / 256, blk, 0, stream>>>(
            xz, conv_wi, conv_bi, xc, xc_bf);
        // xprojT = bf16(xproj_w[i]^T)  [80][1536]
        wcvt_t_k<<<dim3((XPROJ_N + 31) / 32, D_INNER / 32), blk, 0, stream>>>(
            xproj_wi, xprojT, D_INNER, XPROJ_N);
        // xdbl = xc @ xproj_w[i]  (split-K MFMA + reduce; dtin = bf16 pad)
        xproj_gemm_k<<<dim3(M_TOK / 64, KSPLIT), blk, 0, stream>>>(
            xc_bf, xprojT, part);
        xproj_reduce_k<<<(M_TOK * XPROJ_N) / 256, blk, 0, stream>>>(
            part, xdbl, dtin);
        // dt_wT = bf16 padded [1536][64]
        dtw_cvt_k<<<(D_INNER * 64) / 256, blk, 0, stream>>>(dt_wi, dt_wT);
        // delta = softplus(dtin @ dt_w[i] + dt_b[i])
        gemm_bf16<2><<<dim3(M_TOK / 64, D_INNER / 64), blk, 0, stream>>>(
            dtin, dt_wT, delta, D_INNER, 64, dt_bi);
        // y_bf = scan(...)
        scan_k<<<BATCH * (D_INNER / 16), blk, 0, stream>>>(
            delta, xc, xdbl, xz, A_logi, D_parami, y_bf);
        // out_wT = bf16(out_w[i]^T)
        wcvt_t_k<<<dim3(D_MODEL / 32, D_INNER / 32), blk, 0, stream>>>(
            out_wi, out_wT, D_INNER, D_MODEL);
        // h += y_bf @ out_w[i]
        gemm_bf16<3><<<dim3(M_TOK / 64, D_MODEL / 64), blk, 0, stream>>>(
            y_bf, out_wT, h, D_MODEL, D_INNER, nullptr);
    }

    // out = rmsnorm(h, normf_w)  (fp32)
    rmsnorm_k<float><<<M_TOK, blk, 0, stream>>>(h, normf_w, (float*)d_out);
}

// Round 5
// 1700.714 us; speedup vs baseline: 4.1888x; 1.2503x over previous
//
#include <hip/hip_runtime.h>
#include <hip/hip_bf16.h>
#include <cmath>

#define IMG_DIM 512
#define D_MODEL 768
#define N_LAYER 12
#define D_INNER 1536
#define D_STATE 16
#define D_CONV 4
#define DT_RANK 48
#define BATCH 4
#define SEQ 256
#define M_TOK (BATCH * SEQ)               // 1024 token rows
#define XPROJ_N (DT_RANK + 2 * D_STATE)   // 80
#define KSPLIT 8
#define TT 64                             // scan time-tile

typedef __attribute__((ext_vector_type(8))) short bf16x8;
typedef __attribute__((ext_vector_type(4))) float f32x4;

__device__ __forceinline__ float softplus_f(float v) {
    return v > 20.f ? v : log1pf(expf(v));
}

// ---------------------------------------------------------------------------
// Weight transpose + fp32->bf16 convert: W[K][N] -> WT[N][K]; N-guarded
// ---------------------------------------------------------------------------
__global__ __launch_bounds__(256) void wcvt_t_k(
    const float* __restrict__ W, __hip_bfloat16* __restrict__ WT,
    int K, int N)
{
    __shared__ float tile[32][33];
    const int tx = threadIdx.x & 31;
    const int ty4 = (threadIdx.x >> 5) * 4;
    const int n0 = blockIdx.x * 32, k0 = blockIdx.y * 32;
    #pragma unroll
    for (int r = 0; r < 4; ++r)
        tile[ty4 + r][tx] = (n0 + tx < N)
            ? W[(size_t)(k0 + ty4 + r) * N + n0 + tx] : 0.f;
    __syncthreads();
    #pragma unroll
    for (int r = 0; r < 4; ++r)
        if (n0 + ty4 + r < N)
            WT[(size_t)(n0 + ty4 + r) * K + k0 + tx] =
                __float2bfloat16(tile[tx][ty4 + r]);
}

// ---------------------------------------------------------------------------
// Flat fp32 -> bf16 convert
// ---------------------------------------------------------------------------
__global__ __launch_bounds__(256) void cvt_bf16_k(
    const float* __restrict__ in, __hip_bfloat16* __restrict__ out, int n)
{
    int i = blockIdx.x * 256 + threadIdx.x;
    if (i < n) out[i] = __float2bfloat16(in[i]);
}

// ---------------------------------------------------------------------------
// dt_w [48][1536] -> dt_wT [1536][64] bf16, zero-padded k 48..63
// ---------------------------------------------------------------------------
__global__ __launch_bounds__(256) void dtw_cvt_k(
    const float* __restrict__ dt_w, __hip_bfloat16* __restrict__ dtwT)
{
    int idx = blockIdx.x * 256 + threadIdx.x;   // over 1536*64
    int k = idx & 63, n = idx >> 6;
    dtwT[idx] = (k < DT_RANK)
        ? __float2bfloat16(dt_w[(size_t)k * D_INNER + n])
        : __hip_bfloat16(0.f);
}

// ---------------------------------------------------------------------------
// bf16 MFMA GEMM: C[M,N](f32) = A[M,K](bf16) @ BT[N,K](bf16)^T
// 64x64 tile, BK=64, 4 waves (2x2, 32x32 each), XOR-swizzled LDS,
// reg-staged double buffer. Requires K % 64 == 0, N % 64 == 0.
// EPI: 0 = store, 1 = bias+relu, 2 = bias+softplus, 3 = accumulate
// ---------------------------------------------------------------------------
template <int EPI>
__global__ __launch_bounds__(256) void gemm_bf16(
    const __hip_bfloat16* __restrict__ A,
    const __hip_bfloat16* __restrict__ BT,
    float* __restrict__ C, int ldc, int K,
    const float* __restrict__ bias)
{
    __shared__ __align__(16) char lds[2][16384];   // [buf][A 8K | B 8K]
    const int tid = threadIdx.x;
    const int lane = tid & 63;
    const int wid = tid >> 6;
    const int wr = wid >> 1, wc = wid & 1;
    const size_t rowBase = blockIdx.x * 64;
    const size_t colBase = blockIdx.y * 64;

    const int r0 = tid >> 3;
    const int cb0 = (tid & 7) * 16;
    const int wOffA = r0 * 128 + (cb0 ^ ((r0 & 7) << 4));
    const char* gA = (const char*)(A + rowBase * K);
    const char* gB = (const char*)(BT + colBase * K);
    const size_t rowByteOff = (size_t)r0 * K * 2 + cb0;

    const int lrow = lane & 15;
    const int kg = (lane >> 4) * 16;
    const int swz = (lane & 7) << 4;

    f32x4 acc[2][2] = {};

    const int nt = K >> 6;
    float4 ra0, ra1, rb0, rb1;

    ra0 = *(const float4*)(gA + rowByteOff);
    ra1 = *(const float4*)(gA + rowByteOff + (size_t)32 * K * 2);
    rb0 = *(const float4*)(gB + rowByteOff);
    rb1 = *(const float4*)(gB + rowByteOff + (size_t)32 * K * 2);
    *(float4*)(&lds[0][wOffA])        = ra0;
    *(float4*)(&lds[0][wOffA + 4096]) = ra1;
    *(float4*)(&lds[0][wOffA + 8192]) = rb0;
    *(float4*)(&lds[0][wOffA + 12288])= rb1;
    __syncthreads();

    for (int t = 0; t < nt; ++t) {
        const int cur = t & 1;
        if (t + 1 < nt) {
            size_t off = rowByteOff + (size_t)(t + 1) * 128;
            ra0 = *(const float4*)(gA + off);
            ra1 = *(const float4*)(gA + off + (size_t)32 * K * 2);
            rb0 = *(const float4*)(gB + off);
            rb1 = *(const float4*)(gB + off + (size_t)32 * K * 2);
        }
        #pragma unroll
        for (int kk = 0; kk < 2; ++kk) {
            const int col = (kk * 64 + kg) ^ swz;
            bf16x8 a0 = *(const bf16x8*)(&lds[cur][(wr * 32 +      lrow) * 128 + col]);
            bf16x8 a1 = *(const bf16x8*)(&lds[cur][(wr * 32 + 16 + lrow) * 128 + col]);
            bf16x8 b0 = *(const bf16x8*)(&lds[cur][8192 + (wc * 32 +      lrow) * 128 + col]);
            bf16x8 b1 = *(const bf16x8*)(&lds[cur][8192 + (wc * 32 + 16 + lrow) * 128 + col]);
            acc[0][0] = __builtin_amdgcn_mfma_f32_16x16x32_bf16(a0, b0, acc[0][0], 0, 0, 0);
            acc[0][1] = __builtin_amdgcn_mfma_f32_16x16x32_bf16(a0, b1, acc[0][1], 0, 0, 0);
            acc[1][0] = __builtin_amdgcn_mfma_f32_16x16x32_bf16(a1, b0, acc[1][0], 0, 0, 0);
            acc[1][1] = __builtin_amdgcn_mfma_f32_16x16x32_bf16(a1, b1, acc[1][1], 0, 0, 0);
        }
        if (t + 1 < nt) {
            const int nxt = cur ^ 1;
            *(float4*)(&lds[nxt][wOffA])        = ra0;
            *(float4*)(&lds[nxt][wOffA + 4096]) = ra1;
            *(float4*)(&lds[nxt][wOffA + 8192]) = rb0;
            *(float4*)(&lds[nxt][wOffA + 12288])= rb1;
        }
        __syncthreads();
    }

    const int mBase = (int)rowBase + wr * 32 + (lane >> 4) * 4;
    const int nBase = (int)colBase + wc * 32 + (lane & 15);
    #pragma unroll
    for (int i = 0; i < 2; ++i)
        #pragma unroll
        for (int j = 0; j < 2; ++j)
            #pragma unroll
            for (int rg = 0; rg < 4; ++rg) {
                int cc = nBase + j * 16;
                size_t idx = (size_t)(mBase + i * 16 + rg) * ldc + cc;
                float v = acc[i][j][rg];
                if (EPI == 0) {
                    C[idx] = v;
                } else if (EPI == 1) {
                    v += bias[cc];
                    C[idx] = v > 0.f ? v : 0.f;
                } else if (EPI == 2) {
                    v += bias[cc];
                    C[idx] = softplus_f(v);
                } else {
                    C[idx] += v;
                }
            }
}

// ---------------------------------------------------------------------------
// Skinny split-K MFMA GEMM for xproj (no LDS)
// ---------------------------------------------------------------------------
__global__ __launch_bounds__(256) void xproj_gemm_k(
    const __hip_bfloat16* __restrict__ xc_bf,
    const __hip_bfloat16* __restrict__ xprojT,
    float* __restrict__ part)
{
    const int lane = threadIdx.x & 63;
    const int w = threadIdx.x >> 6;
    const int m0 = blockIdx.x * 64 + w * 16;
    const int ks = blockIdx.y;
    const int KS = D_INNER / KSPLIT;          // 192
    const int k0 = ks * KS;

    const int arow = m0 + (lane & 15);
    const int kgrp = (lane >> 4) * 8;

    f32x4 acc[5] = {};
    const __hip_bfloat16* ap = xc_bf + (size_t)arow * D_INNER + kgrp;
    const __hip_bfloat16* bp = xprojT + (size_t)(lane & 15) * D_INNER + kgrp;

    for (int k = k0; k < k0 + KS; k += 32) {
        bf16x8 a = *(const bf16x8*)(ap + k);
        #pragma unroll
        for (int f = 0; f < 5; ++f) {
            bf16x8 b = *(const bf16x8*)(bp + (size_t)f * 16 * D_INNER + k);
            acc[f] = __builtin_amdgcn_mfma_f32_16x16x32_bf16(a, b, acc[f], 0, 0, 0);
        }
    }

    float* out = part + (size_t)ks * M_TOK * XPROJ_N;
    const int rowb = blockIdx.x * 64 + w * 16 + (lane >> 4) * 4;
    #pragma unroll
    for (int f = 0; f < 5; ++f)
        #pragma unroll
        for (int rg = 0; rg < 4; ++rg)
            out[(size_t)(rowb + rg) * XPROJ_N + f * 16 + (lane & 15)] = acc[f][rg];
}

// ---------------------------------------------------------------------------
// Reduce split-K partials -> xdbl fp32 [1024][80]; cols<48 also -> dtin bf16
// ---------------------------------------------------------------------------
__global__ __launch_bounds__(256) void xproj_reduce_k(
    const float* __restrict__ part, float* __restrict__ xdbl,
    __hip_bfloat16* __restrict__ dtin)
{
    int idx = blockIdx.x * 256 + threadIdx.x;   // < 1024*80
    float s = 0.f;
    #pragma unroll
    for (int p = 0; p < KSPLIT; ++p)
        s += part[(size_t)p * M_TOK * XPROJ_N + idx];
    xdbl[idx] = s;
    int col = idx % XPROJ_N;
    int row = idx / XPROJ_N;
    if (col < DT_RANK)
        dtin[(size_t)row * 64 + col] = __float2bfloat16(s);
}

// ---------------------------------------------------------------------------
// RMSNorm: one block per token row; templated output type
// ---------------------------------------------------------------------------
template <typename OT>
__global__ __launch_bounds__(256) void rmsnorm_k(
    const float* __restrict__ x, const float* __restrict__ w,
    OT* __restrict__ o)
{
    const int row = blockIdx.x;
    const float* xr = x + (size_t)row * D_MODEL;
    float v[3];
    float s = 0.f;
    #pragma unroll
    for (int i = 0; i < 3; ++i) {
        v[i] = xr[threadIdx.x + i * 256];
        s = fmaf(v[i], v[i], s);
    }
    #pragma unroll
    for (int off = 32; off > 0; off >>= 1) s += __shfl_down(s, off);
    __shared__ float red[4];
    if ((threadIdx.x & 63) == 0) red[threadIdx.x >> 6] = s;
    __syncthreads();
    float tot = red[0] + red[1] + red[2] + red[3];
    float r = rsqrtf(tot * (1.f / D_MODEL) + 1e-5f);
    OT* orow = o + (size_t)row * D_MODEL;
    #pragma unroll
    for (int i = 0; i < 3; ++i) {
        int c = threadIdx.x + i * 256;
        orow[c] = (OT)(v[i] * r * w[c]);
    }
}

// ---------------------------------------------------------------------------
// Causal depthwise conv (width 4) + bias + silu; fp32 + bf16 outputs
// ---------------------------------------------------------------------------
__global__ __launch_bounds__(256) void conv_silu_k(
    const float* __restrict__ xz, const float* __restrict__ cw,
    const float* __restrict__ cb, float* __restrict__ xc,
    __hip_bfloat16* __restrict__ xc_bf)
{
    int idx = blockIdx.x * 256 + threadIdx.x;
    int d = idx % D_INNER;
    int bt = idx / D_INNER;
    int t = bt & (SEQ - 1);
    int b = bt >> 8;
    float acc = cb[d];
    #pragma unroll
    for (int k = 0; k < 4; ++k) {
        int tt = t - 3 + k;
        if (tt >= 0)
            acc = fmaf(xz[(size_t)(b * SEQ + tt) * (2 * D_INNER) + d], cw[d * 4 + k], acc);
    }
    float sig = 1.f / (1.f + expf(-acc));
    float v = acc * sig;
    xc[idx] = v;
    xc_bf[idx] = __float2bfloat16(v);
}

// ---------------------------------------------------------------------------
// Selective scan, LDS-tiled: block = (b, 16 d's), 256 thr (thread = (d,n)).
// Time processed in 4 tiles of TT=64: coalesced float4 staging into LDS
// (silu(res) precomputed), next-tile loads issued before compute, per-step
// critical path is LDS broadcast reads + 1 exp + fma + 4 shfl.
// y written per-tile as coalesced bf16.
// ---------------------------------------------------------------------------
__global__ __launch_bounds__(256) void scan_k(
    const float* __restrict__ delta,
    const float* __restrict__ xc,
    const float* __restrict__ xdbl,
    const float* __restrict__ xz,
    const float* __restrict__ A_log,
    const float* __restrict__ D_param,
    __hip_bfloat16* __restrict__ y)
{
    __shared__ float sd[TT][16];   // delta
    __shared__ float su[TT][16];   // u
    __shared__ float ss[TT][16];   // silu(res)
    __shared__ float sB[TT][16];
    __shared__ float sC[TT][16];
    __shared__ __hip_bfloat16 sy[TT][16];

    const int tid = threadIdx.x;
    const int n  = tid & 15;
    const int dd = tid >> 4;
    const int blocksPerB = D_INNER / 16;          // 96
    const int b  = blockIdx.x / blocksPerB;
    const int d0 = (blockIdx.x % blocksPerB) * 16;
    const int d  = d0 + dd;

    const float A  = -expf(A_log[(size_t)d * D_STATE + n]);
    const float Dp = D_param[d];
    float h = 0.f;

    // staging coords: delta/u/res/y tiles are [64][16] -> 4 el per thread
    const int srow = tid >> 2;            // 0..63
    const int scol = (tid & 3) * 4;       // 0,4,8,12
    // BC tile [64][32] -> 8 el per thread (2 float4)
    const int brow0 = tid >> 3;           // 0..31
    const int bcol  = (tid & 7) * 4;      // 0..28
    const int brow1 = brow0 + 32;
    float* bdst0 = (bcol < 16) ? &sB[brow0][bcol] : &sC[brow0][bcol - 16];
    float* bdst1 = (bcol < 16) ? &sB[brow1][bcol] : &sC[brow1][bcol - 16];

    const float* dsrc = delta + ((size_t)b * SEQ + srow) * D_INNER + d0 + scol;
    const float* usrc = xc    + ((size_t)b * SEQ + srow) * D_INNER + d0 + scol;
    const float* rsrc = xz    + ((size_t)b * SEQ + srow) * 2 * D_INNER + D_INNER + d0 + scol;
    const float* bsrc0 = xdbl + ((size_t)b * SEQ + brow0) * XPROJ_N + DT_RANK + bcol;
    const float* bsrc1 = xdbl + ((size_t)b * SEQ + brow1) * XPROJ_N + DT_RANK + bcol;
    __hip_bfloat16* ydst = y + ((size_t)b * SEQ + srow) * D_INNER + d0 + scol;

    // prologue: load tile 0 into regs
    float4 rd = *(const float4*)dsrc;
    float4 ru = *(const float4*)usrc;
    float4 rr = *(const float4*)rsrc;
    float4 rb0 = *(const float4*)bsrc0;
    float4 rb1 = *(const float4*)bsrc1;

    for (int tile = 0; tile < SEQ / TT; ++tile) {
        // write staged regs to LDS (silu applied to res here)
        *(float4*)&sd[srow][scol] = rd;
        *(float4*)&su[srow][scol] = ru;
        float4 sv;
        sv.x = rr.x / (1.f + expf(-rr.x));
        sv.y = rr.y / (1.f + expf(-rr.y));
        sv.z = rr.z / (1.f + expf(-rr.z));
        sv.w = rr.w / (1.f + expf(-rr.w));
        *(float4*)&ss[srow][scol] = sv;
        *(float4*)bdst0 = rb0;
        *(float4*)bdst1 = rb1;
        __syncthreads();

        // issue next-tile loads (latency hides under compute)
        if (tile + 1 < SEQ / TT) {
            size_t off = (size_t)(tile + 1) * TT;
            rd  = *(const float4*)(dsrc + off * D_INNER);
            ru  = *(const float4*)(usrc + off * D_INNER);
            rr  = *(const float4*)(rsrc + off * 2 * D_INNER);
            rb0 = *(const float4*)(bsrc0 + off * XPROJ_N);
            rb1 = *(const float4*)(bsrc1 + off * XPROJ_N);
        }

        // 64 scan steps from LDS
        #pragma unroll 8
        for (int t = 0; t < TT; ++t) {
            float dv = sd[t][dd];
            float uu = su[t][dd];
            float Bv = sB[t][n];
            float Cv = sC[t][n];
            float dA = expf(dv * A);
            h = fmaf(dA, h, dv * uu * Bv);
            float pv = h * Cv;
            pv += __shfl_xor(pv, 1);
            pv += __shfl_xor(pv, 2);
            pv += __shfl_xor(pv, 4);
            pv += __shfl_xor(pv, 8);
            float out = (pv + uu * Dp) * ss[t][dd];
            if (n == 0) sy[t][dd] = __float2bfloat16(out);
        }
        __syncthreads();

        // cooperative coalesced store of y tile (4 bf16 per thread)
        *(ushort4*)(ydst + (size_t)tile * TT * D_INNER) =
            *(const ushort4*)&sy[srow][scol];
    }
}

// ---------------------------------------------------------------------------
// Launch
// ---------------------------------------------------------------------------
extern "C" void kernel_launch(void* const* d_in, const int* in_sizes, int n_in,
                              void* d_out, int out_size, void* d_ws, size_t ws_size,
                              hipStream_t stream)
{
    const float* frames  = (const float*)d_in[0];
    const float* fproj_w = (const float*)d_in[1];
    const float* fproj_b = (const float*)d_in[2];
    const float* norm_w  = (const float*)d_in[3];
    const float* in_w    = (const float*)d_in[4];
    const float* conv_w  = (const float*)d_in[5];
    const float* conv_b  = (const float*)d_in[6];
    const float* xproj_w = (const float*)d_in[7];
    const float* dt_w    = (const float*)d_in[8];
    const float* dt_b    = (const float*)d_in[9];
    const float* A_log   = (const float*)d_in[10];
    const float* D_param = (const float*)d_in[11];
    const float* out_w   = (const float*)d_in[12];
    const float* normf_w = (const float*)d_in[13];

    // workspace layout
    char* ws = (char*)d_ws;
    float* h      = (float*)ws;                   ws += (size_t)M_TOK * D_MODEL * 4;
    float* xz     = (float*)ws;                   ws += (size_t)M_TOK * 2 * D_INNER * 4;
    float* xc     = (float*)ws;                   ws += (size_t)M_TOK * D_INNER * 4;
    float* xdbl   = (float*)ws;                   ws += (size_t)M_TOK * XPROJ_N * 4;
    float* delta  = (float*)ws;                   ws += (size_t)M_TOK * D_INNER * 4;
    float* part   = (float*)ws;                   ws += (size_t)KSPLIT * M_TOK * XPROJ_N * 4;
    __hip_bfloat16* x_bf   = (__hip_bfloat16*)ws; ws += (size_t)M_TOK * D_MODEL * 2;
    __hip_bfloat16* y_bf   = (__hip_bfloat16*)ws; ws += (size_t)M_TOK * D_INNER * 2;
    __hip_bfloat16* xc_bf  = (__hip_bfloat16*)ws; ws += (size_t)M_TOK * D_INNER * 2;
    __hip_bfloat16* dtin   = (__hip_bfloat16*)ws; ws += (size_t)M_TOK * 64 * 2;
    __hip_bfloat16* fr_bf  = (__hip_bfloat16*)ws; ws += (size_t)M_TOK * IMG_DIM * 2;
    __hip_bfloat16* fp_wT  = (__hip_bfloat16*)ws; ws += (size_t)D_MODEL * IMG_DIM * 2;
    __hip_bfloat16* in_wT  = (__hip_bfloat16*)ws; ws += (size_t)(2 * D_INNER) * D_MODEL * 2;
    __hip_bfloat16* out_wT = (__hip_bfloat16*)ws; ws += (size_t)D_MODEL * D_INNER * 2;
    __hip_bfloat16* xprojT = (__hip_bfloat16*)ws; ws += (size_t)XPROJ_N * D_INNER * 2;
    __hip_bfloat16* dt_wT  = (__hip_bfloat16*)ws; ws += (size_t)D_INNER * 64 * 2;

    dim3 blk(256);

    // zero dtin once per call (pad cols 48..63 must be 0)
    hipMemsetAsync(dtin, 0, (size_t)M_TOK * 64 * 2, stream);

    // h = relu(frames @ fproj_w + fproj_b)   (bf16 MFMA)
    cvt_bf16_k<<<(M_TOK * IMG_DIM) / 256, blk, 0, stream>>>(
        frames, fr_bf, M_TOK * IMG_DIM);
    wcvt_t_k<<<dim3(D_MODEL / 32, IMG_DIM / 32), blk, 0, stream>>>(
        fproj_w, fp_wT, IMG_DIM, D_MODEL);
    gemm_bf16<1><<<dim3(M_TOK / 64, D_MODEL / 64), blk, 0, stream>>>(
        fr_bf, fp_wT, h, D_MODEL, IMG_DIM, fproj_b);

    for (int i = 0; i < N_LAYER; ++i) {
        const float* in_wi    = in_w    + (size_t)i * D_MODEL * 2 * D_INNER;
        const float* conv_wi  = conv_w  + (size_t)i * D_INNER * D_CONV;
        const float* conv_bi  = conv_b  + (size_t)i * D_INNER;
        const float* xproj_wi = xproj_w + (size_t)i * D_INNER * XPROJ_N;
        const float* dt_wi    = dt_w    + (size_t)i * DT_RANK * D_INNER;
        const float* dt_bi    = dt_b    + (size_t)i * D_INNER;
        const float* A_logi   = A_log   + (size_t)i * D_INNER * D_STATE;
        const float* D_parami = D_param + (size_t)i * D_INNER;
        const float* out_wi   = out_w   + (size_t)i * D_INNER * D_MODEL;
        const float* norm_wi  = norm_w  + (size_t)i * D_MODEL;

        // x_bf = bf16(rmsnorm(h))
        rmsnorm_k<__hip_bfloat16><<<M_TOK, blk, 0, stream>>>(h, norm_wi, x_bf);
        // in_wT = bf16(in_w[i]^T)
        wcvt_t_k<<<dim3(2 * D_INNER / 32, D_MODEL / 32), blk, 0, stream>>>(
            in_wi, in_wT, D_MODEL, 2 * D_INNER);
        // xz = x_bf @ in_w[i]
        gemm_bf16<0><<<dim3(M_TOK / 64, (2 * D_INNER) / 64), blk, 0, stream>>>(
            x_bf, in_wT, xz, 2 * D_INNER, D_MODEL, nullptr);
        // xc = silu(conv(xi) + conv_b)  (+ bf16 copy)
        conv_silu_k<<<(M_TOK * D_INNER) / 256, blk, 0, stream>>>(
            xz, conv_wi, conv_bi, xc, xc_bf);
        // xprojT = bf16(xproj_w[i]^T)  [80][1536]
        wcvt_t_k<<<dim3((XPROJ_N + 31) / 32, D_INNER / 32), blk, 0, stream>>>(
            xproj_wi, xprojT, D_INNER, XPROJ_N);
        // xdbl = xc @ xproj_w[i]  (split-K MFMA + reduce; dtin = bf16 pad)
        xproj_gemm_k<<<dim3(M_TOK / 64, KSPLIT), blk, 0, stream>>>(
            xc_bf, xprojT, part);
        xproj_reduce_k<<<(M_TOK * XPROJ_N) / 256, blk, 0, stream>>>(
            part, xdbl, dtin);
        // dt_wT = bf16 padded [1536][64]
        dtw_cvt_k<<<(D_INNER * 64) / 256, blk, 0, stream>>>(dt_wi, dt_wT);
        // delta = softplus(dtin @ dt_w[i] + dt_b[i])
        gemm_bf16<2><<<dim3(M_TOK / 64, D_INNER / 64), blk, 0, stream>>>(
            dtin, dt_wT, delta, D_INNER, 64, dt_bi);
        // y_bf = scan(...)  (LDS-tiled)
        scan_k<<<BATCH * (D_INNER / 16), blk, 0, stream>>>(
            delta, xc, xdbl, xz, A_logi, D_parami, y_bf);
        // out_wT = bf16(out_w[i]^T)
        wcvt_t_k<<<dim3(D_MODEL / 32, D_INNER / 32), blk, 0, stream>>>(
            out_wi, out_wT, D_INNER, D_MODEL);
        // h += y_bf @ out_w[i]
        gemm_bf16<3><<<dim3(M_TOK / 64, D_MODEL / 64), blk, 0, stream>>>(
            y_bf, out_wT, h, D_MODEL, D_INNER, nullptr);
    }

    // out = rmsnorm(h, normf_w)  (fp32)
    rmsnorm_k<float><<<M_TOK, blk, 0, stream>>>(h, normf_w, (float*)d_out);
}

// Round 6
// 1424.112 us; speedup vs baseline: 5.0024x; 1.1942x over previous
//
#include <hip/hip_runtime.h>
#include <hip/hip_bf16.h>
#include <cmath>

#define IMG_DIM 512
#define D_MODEL 768
#define N_LAYER 12
#define D_INNER 1536
#define D_STATE 16
#define D_CONV 4
#define DT_RANK 48
#define BATCH 4
#define SEQ 256
#define M_TOK (BATCH * SEQ)               // 1024 token rows
#define XPROJ_N (DT_RANK + 2 * D_STATE)   // 80
#define KSPLIT 8
#define NCHUNK 16
#define CLEN 16                           // SEQ / NCHUNK
#define LOG2E 1.4426950408889634f

typedef __attribute__((ext_vector_type(8))) short bf16x8;
typedef __attribute__((ext_vector_type(4))) float f32x4;

__device__ __forceinline__ float softplus_f(float v) {
    return v > 20.f ? v : log1pf(expf(v));
}

// ---------------------------------------------------------------------------
// Weight transpose + fp32->bf16 convert: W[K][N] -> WT[N][K]; N-guarded
// ---------------------------------------------------------------------------
__global__ __launch_bounds__(256) void wcvt_t_k(
    const float* __restrict__ W, __hip_bfloat16* __restrict__ WT,
    int K, int N)
{
    __shared__ float tile[32][33];
    const int tx = threadIdx.x & 31;
    const int ty4 = (threadIdx.x >> 5) * 4;
    const int n0 = blockIdx.x * 32, k0 = blockIdx.y * 32;
    #pragma unroll
    for (int r = 0; r < 4; ++r)
        tile[ty4 + r][tx] = (n0 + tx < N)
            ? W[(size_t)(k0 + ty4 + r) * N + n0 + tx] : 0.f;
    __syncthreads();
    #pragma unroll
    for (int r = 0; r < 4; ++r)
        if (n0 + ty4 + r < N)
            WT[(size_t)(n0 + ty4 + r) * K + k0 + tx] =
                __float2bfloat16(tile[tx][ty4 + r]);
}

// ---------------------------------------------------------------------------
// Flat fp32 -> bf16 convert
// ---------------------------------------------------------------------------
__global__ __launch_bounds__(256) void cvt_bf16_k(
    const float* __restrict__ in, __hip_bfloat16* __restrict__ out, int n)
{
    int i = blockIdx.x * 256 + threadIdx.x;
    if (i < n) out[i] = __float2bfloat16(in[i]);
}

// ---------------------------------------------------------------------------
// dt_w [48][1536] -> dt_wT [1536][64] bf16, zero-padded k 48..63
// ---------------------------------------------------------------------------
__global__ __launch_bounds__(256) void dtw_cvt_k(
    const float* __restrict__ dt_w, __hip_bfloat16* __restrict__ dtwT)
{
    int idx = blockIdx.x * 256 + threadIdx.x;   // over 1536*64
    int k = idx & 63, n = idx >> 6;
    dtwT[idx] = (k < DT_RANK)
        ? __float2bfloat16(dt_w[(size_t)k * D_INNER + n])
        : __hip_bfloat16(0.f);
}

// ---------------------------------------------------------------------------
// A2[d][n] = -exp(A_log[d][n]) * log2(e)   (so dA = exp2(dv * A2))
// ---------------------------------------------------------------------------
__global__ __launch_bounds__(256) void a2_k(
    const float* __restrict__ A_log, float* __restrict__ A2)
{
    int idx = blockIdx.x * 256 + threadIdx.x;   // < 1536*16
    A2[idx] = -expf(A_log[idx]) * LOG2E;
}

// ---------------------------------------------------------------------------
// bf16 MFMA GEMM: C[M,N](f32) = A[M,K](bf16) @ BT[N,K](bf16)^T
// 64x64 tile, BK=64, 4 waves (2x2), XOR-swizzled LDS, reg-staged dbuf.
// EPI: 0 = store, 1 = bias+relu, 2 = bias+softplus, 3 = accumulate
// ---------------------------------------------------------------------------
template <int EPI>
__global__ __launch_bounds__(256) void gemm_bf16(
    const __hip_bfloat16* __restrict__ A,
    const __hip_bfloat16* __restrict__ BT,
    float* __restrict__ C, int ldc, int K,
    const float* __restrict__ bias)
{
    __shared__ __align__(16) char lds[2][16384];   // [buf][A 8K | B 8K]
    const int tid = threadIdx.x;
    const int lane = tid & 63;
    const int wid = tid >> 6;
    const int wr = wid >> 1, wc = wid & 1;
    const size_t rowBase = blockIdx.x * 64;
    const size_t colBase = blockIdx.y * 64;

    const int r0 = tid >> 3;
    const int cb0 = (tid & 7) * 16;
    const int wOffA = r0 * 128 + (cb0 ^ ((r0 & 7) << 4));
    const char* gA = (const char*)(A + rowBase * K);
    const char* gB = (const char*)(BT + colBase * K);
    const size_t rowByteOff = (size_t)r0 * K * 2 + cb0;

    const int lrow = lane & 15;
    const int kg = (lane >> 4) * 16;
    const int swz = (lane & 7) << 4;

    f32x4 acc[2][2] = {};

    const int nt = K >> 6;
    float4 ra0, ra1, rb0, rb1;

    ra0 = *(const float4*)(gA + rowByteOff);
    ra1 = *(const float4*)(gA + rowByteOff + (size_t)32 * K * 2);
    rb0 = *(const float4*)(gB + rowByteOff);
    rb1 = *(const float4*)(gB + rowByteOff + (size_t)32 * K * 2);
    *(float4*)(&lds[0][wOffA])        = ra0;
    *(float4*)(&lds[0][wOffA + 4096]) = ra1;
    *(float4*)(&lds[0][wOffA + 8192]) = rb0;
    *(float4*)(&lds[0][wOffA + 12288])= rb1;
    __syncthreads();

    for (int t = 0; t < nt; ++t) {
        const int cur = t & 1;
        if (t + 1 < nt) {
            size_t off = rowByteOff + (size_t)(t + 1) * 128;
            ra0 = *(const float4*)(gA + off);
            ra1 = *(const float4*)(gA + off + (size_t)32 * K * 2);
            rb0 = *(const float4*)(gB + off);
            rb1 = *(const float4*)(gB + off + (size_t)32 * K * 2);
        }
        #pragma unroll
        for (int kk = 0; kk < 2; ++kk) {
            const int col = (kk * 64 + kg) ^ swz;
            bf16x8 a0 = *(const bf16x8*)(&lds[cur][(wr * 32 +      lrow) * 128 + col]);
            bf16x8 a1 = *(const bf16x8*)(&lds[cur][(wr * 32 + 16 + lrow) * 128 + col]);
            bf16x8 b0 = *(const bf16x8*)(&lds[cur][8192 + (wc * 32 +      lrow) * 128 + col]);
            bf16x8 b1 = *(const bf16x8*)(&lds[cur][8192 + (wc * 32 + 16 + lrow) * 128 + col]);
            acc[0][0] = __builtin_amdgcn_mfma_f32_16x16x32_bf16(a0, b0, acc[0][0], 0, 0, 0);
            acc[0][1] = __builtin_amdgcn_mfma_f32_16x16x32_bf16(a0, b1, acc[0][1], 0, 0, 0);
            acc[1][0] = __builtin_amdgcn_mfma_f32_16x16x32_bf16(a1, b0, acc[1][0], 0, 0, 0);
            acc[1][1] = __builtin_amdgcn_mfma_f32_16x16x32_bf16(a1, b1, acc[1][1], 0, 0, 0);
        }
        if (t + 1 < nt) {
            const int nxt = cur ^ 1;
            *(float4*)(&lds[nxt][wOffA])        = ra0;
            *(float4*)(&lds[nxt][wOffA + 4096]) = ra1;
            *(float4*)(&lds[nxt][wOffA + 8192]) = rb0;
            *(float4*)(&lds[nxt][wOffA + 12288])= rb1;
        }
        __syncthreads();
    }

    const int mBase = (int)rowBase + wr * 32 + (lane >> 4) * 4;
    const int nBase = (int)colBase + wc * 32 + (lane & 15);
    #pragma unroll
    for (int i = 0; i < 2; ++i)
        #pragma unroll
        for (int j = 0; j < 2; ++j)
            #pragma unroll
            for (int rg = 0; rg < 4; ++rg) {
                int cc = nBase + j * 16;
                size_t idx = (size_t)(mBase + i * 16 + rg) * ldc + cc;
                float v = acc[i][j][rg];
                if (EPI == 0) {
                    C[idx] = v;
                } else if (EPI == 1) {
                    v += bias[cc];
                    C[idx] = v > 0.f ? v : 0.f;
                } else if (EPI == 2) {
                    v += bias[cc];
                    C[idx] = softplus_f(v);
                } else {
                    C[idx] += v;
                }
            }
}

// ---------------------------------------------------------------------------
// Skinny split-K MFMA GEMM for xproj (no LDS)
// ---------------------------------------------------------------------------
__global__ __launch_bounds__(256) void xproj_gemm_k(
    const __hip_bfloat16* __restrict__ xc_bf,
    const __hip_bfloat16* __restrict__ xprojT,
    float* __restrict__ part)
{
    const int lane = threadIdx.x & 63;
    const int w = threadIdx.x >> 6;
    const int m0 = blockIdx.x * 64 + w * 16;
    const int ks = blockIdx.y;
    const int KS = D_INNER / KSPLIT;          // 192
    const int k0 = ks * KS;

    const int arow = m0 + (lane & 15);
    const int kgrp = (lane >> 4) * 8;

    f32x4 acc[5] = {};
    const __hip_bfloat16* ap = xc_bf + (size_t)arow * D_INNER + kgrp;
    const __hip_bfloat16* bp = xprojT + (size_t)(lane & 15) * D_INNER + kgrp;

    for (int k = k0; k < k0 + KS; k += 32) {
        bf16x8 a = *(const bf16x8*)(ap + k);
        #pragma unroll
        for (int f = 0; f < 5; ++f) {
            bf16x8 b = *(const bf16x8*)(bp + (size_t)f * 16 * D_INNER + k);
            acc[f] = __builtin_amdgcn_mfma_f32_16x16x32_bf16(a, b, acc[f], 0, 0, 0);
        }
    }

    float* out = part + (size_t)ks * M_TOK * XPROJ_N;
    const int rowb = blockIdx.x * 64 + w * 16 + (lane >> 4) * 4;
    #pragma unroll
    for (int f = 0; f < 5; ++f)
        #pragma unroll
        for (int rg = 0; rg < 4; ++rg)
            out[(size_t)(rowb + rg) * XPROJ_N + f * 16 + (lane & 15)] = acc[f][rg];
}

// ---------------------------------------------------------------------------
// Reduce split-K partials -> xdbl fp32 [1024][80]; cols<48 also -> dtin bf16
// ---------------------------------------------------------------------------
__global__ __launch_bounds__(256) void xproj_reduce_k(
    const float* __restrict__ part, float* __restrict__ xdbl,
    __hip_bfloat16* __restrict__ dtin)
{
    int idx = blockIdx.x * 256 + threadIdx.x;   // < 1024*80
    float s = 0.f;
    #pragma unroll
    for (int p = 0; p < KSPLIT; ++p)
        s += part[(size_t)p * M_TOK * XPROJ_N + idx];
    xdbl[idx] = s;
    int col = idx % XPROJ_N;
    int row = idx / XPROJ_N;
    if (col < DT_RANK)
        dtin[(size_t)row * 64 + col] = __float2bfloat16(s);
}

// ---------------------------------------------------------------------------
// RMSNorm: one block per token row; templated output type
// ---------------------------------------------------------------------------
template <typename OT>
__global__ __launch_bounds__(256) void rmsnorm_k(
    const float* __restrict__ x, const float* __restrict__ w,
    OT* __restrict__ o)
{
    const int row = blockIdx.x;
    const float* xr = x + (size_t)row * D_MODEL;
    float v[3];
    float s = 0.f;
    #pragma unroll
    for (int i = 0; i < 3; ++i) {
        v[i] = xr[threadIdx.x + i * 256];
        s = fmaf(v[i], v[i], s);
    }
    #pragma unroll
    for (int off = 32; off > 0; off >>= 1) s += __shfl_down(s, off);
    __shared__ float red[4];
    if ((threadIdx.x & 63) == 0) red[threadIdx.x >> 6] = s;
    __syncthreads();
    float tot = red[0] + red[1] + red[2] + red[3];
    float r = rsqrtf(tot * (1.f / D_MODEL) + 1e-5f);
    OT* orow = o + (size_t)row * D_MODEL;
    #pragma unroll
    for (int i = 0; i < 3; ++i) {
        int c = threadIdx.x + i * 256;
        orow[c] = (OT)(v[i] * r * w[c]);
    }
}

// ---------------------------------------------------------------------------
// Causal depthwise conv (width 4) + bias + silu; fp32 + bf16 outputs
// ---------------------------------------------------------------------------
__global__ __launch_bounds__(256) void conv_silu_k(
    const float* __restrict__ xz, const float* __restrict__ cw,
    const float* __restrict__ cb, float* __restrict__ xc,
    __hip_bfloat16* __restrict__ xc_bf)
{
    int idx = blockIdx.x * 256 + threadIdx.x;
    int d = idx % D_INNER;
    int bt = idx / D_INNER;
    int t = bt & (SEQ - 1);
    int b = bt >> 8;
    float acc = cb[d];
    #pragma unroll
    for (int k = 0; k < 4; ++k) {
        int tt = t - 3 + k;
        if (tt >= 0)
            acc = fmaf(xz[(size_t)(b * SEQ + tt) * (2 * D_INNER) + d], cw[d * 4 + k], acc);
    }
    float sig = 1.f / (1.f + expf(-acc));
    float v = acc * sig;
    xc[idx] = v;
    xc_bf[idx] = __float2bfloat16(v);
}

// ---------------------------------------------------------------------------
// Chunked selective scan, phase 1: per (b, chunk, d) compute within-chunk
// scan from h=0. Writes cumdv, ypart (incl. u*D), chunk-final h.
// Thread = one d; 16 states in registers; no cross-lane ops.
// ---------------------------------------------------------------------------
__global__ __launch_bounds__(256) void scan_part_k(
    const float* __restrict__ delta,
    const float* __restrict__ xc,
    const float* __restrict__ xdbl,
    const float* __restrict__ A2,
    const float* __restrict__ D_param,
    float* __restrict__ cumdv,
    float* __restrict__ ypart,
    float* __restrict__ hpart)
{
    __shared__ float sBC[CLEN][32];   // [step][B 0..15 | C 16..31]
    const int tid = threadIdx.x;
    const int dgrp  = blockIdx.x % 6;
    const int chunk = (blockIdx.x / 6) & (NCHUNK - 1);
    const int b     = blockIdx.x / (6 * NCHUNK);
    const int d  = dgrp * 256 + tid;
    const int t0 = chunk * CLEN;

    {
        int r = tid >> 5, c = tid & 31;
        sBC[r][c]     = xdbl[(size_t)(b * SEQ + t0 + r) * XPROJ_N + DT_RANK + c];
        sBC[r + 8][c] = xdbl[(size_t)(b * SEQ + t0 + r + 8) * XPROJ_N + DT_RANK + c];
    }

    float a2[16];
    {
        const float4* ap = (const float4*)(A2 + (size_t)d * 16);
        #pragma unroll
        for (int q = 0; q < 4; ++q) {
            float4 v = ap[q];
            a2[q * 4 + 0] = v.x; a2[q * 4 + 1] = v.y;
            a2[q * 4 + 2] = v.z; a2[q * 4 + 3] = v.w;
        }
    }
    const float Dp = D_param[d];

    const size_t base = (size_t)(b * SEQ + t0) * D_INNER + d;
    const float* dp = delta + base;
    const float* up = xc + base;

    float dvv[CLEN], uvv[CLEN];
    #pragma unroll
    for (int s = 0; s < CLEN; ++s) {
        dvv[s] = dp[(size_t)s * D_INNER];
        uvv[s] = up[(size_t)s * D_INNER];
    }
    __syncthreads();

    float h[16];
    #pragma unroll
    for (int n = 0; n < 16; ++n) h[n] = 0.f;
    float cum = 0.f;

    #pragma unroll
    for (int s = 0; s < CLEN; ++s) {
        float dv = dvv[s], u = uvv[s];
        cum += dv;
        cumdv[base + (size_t)s * D_INNER] = cum;
        float du = dv * u;
        float yv = 0.f;
        #pragma unroll
        for (int n = 0; n < 16; ++n) {
            float dA = exp2f(dv * a2[n]);
            h[n] = fmaf(dA, h[n], du * sBC[s][n]);
            yv = fmaf(h[n], sBC[s][16 + n], yv);
        }
        ypart[base + (size_t)s * D_INNER] = fmaf(u, Dp, yv);
    }

    float4* hp = (float4*)(hpart + (((size_t)b * NCHUNK + chunk) * D_INNER + d) * 16);
    #pragma unroll
    for (int q = 0; q < 4; ++q) {
        float4 v;
        v.x = h[q * 4 + 0]; v.y = h[q * 4 + 1];
        v.z = h[q * 4 + 2]; v.w = h[q * 4 + 3];
        hp[q] = v;
    }
}

// ---------------------------------------------------------------------------
// Phase 2: serial prefix over chunks. Thread = (b,d,n).
// hin[c] = state entering chunk c.
// ---------------------------------------------------------------------------
__global__ __launch_bounds__(256) void scan_pref_k(
    const float* __restrict__ cumdv,
    const float* __restrict__ hpart,
    const float* __restrict__ A2,
    float* __restrict__ hinb)
{
    int idx = blockIdx.x * 256 + threadIdx.x;   // < 4*1536*16
    int n = idx & 15;
    int r = idx >> 4;
    int d = r % D_INNER;
    int b = r / D_INNER;
    float a2 = A2[(size_t)d * 16 + n];
    float hin = 0.f;
    #pragma unroll
    for (int c = 0; c < NCHUNK; ++c) {
        hinb[(((size_t)b * NCHUNK + c) * D_INNER + d) * 16 + n] = hin;
        float sdv = cumdv[(size_t)(b * SEQ + c * CLEN + CLEN - 1) * D_INNER + d];
        float hp  = hpart[(((size_t)b * NCHUNK + c) * D_INNER + d) * 16 + n];
        hin = fmaf(hin, exp2f(a2 * sdv), hp);
    }
}

// ---------------------------------------------------------------------------
// Phase 3: elementwise fix-up over (b,t,d):
// y = (ypart + sum_n C[n]*exp2(A2[n]*cumdv)*hin[n]) * silu(res)
// ---------------------------------------------------------------------------
__global__ __launch_bounds__(256) void scan_fix_k(
    const float* __restrict__ ypart,
    const float* __restrict__ cumdv,
    const float* __restrict__ xdbl,
    const float* __restrict__ xz,
    const float* __restrict__ A2,
    const float* __restrict__ hinb,
    __hip_bfloat16* __restrict__ y)
{
    __shared__ float sC[16];
    int idx = blockIdx.x * 256 + threadIdx.x;   // bt constant per block (1536 = 6*256)
    int d = idx % D_INNER;
    int bt = idx / D_INNER;
    int t = bt & (SEQ - 1);
    int b = bt >> 8;
    int chunk = t >> 4;   // CLEN = 16

    if (threadIdx.x < 16)
        sC[threadIdx.x] = xdbl[(size_t)bt * XPROJ_N + DT_RANK + D_STATE + threadIdx.x];
    __syncthreads();

    float cum = cumdv[idx];
    float yp  = ypart[idx];
    float res = xz[(size_t)bt * 2 * D_INNER + D_INNER + d];

    const float4* hp = (const float4*)(hinb + (((size_t)b * NCHUNK + chunk) * D_INNER + d) * 16);
    const float4* ap = (const float4*)(A2 + (size_t)d * 16);

    float corr = 0.f;
    #pragma unroll
    for (int q = 0; q < 4; ++q) {
        float4 hv = hp[q];
        float4 av = ap[q];
        corr = fmaf(exp2f(av.x * cum) * hv.x, sC[q * 4 + 0], corr);
        corr = fmaf(exp2f(av.y * cum) * hv.y, sC[q * 4 + 1], corr);
        corr = fmaf(exp2f(av.z * cum) * hv.z, sC[q * 4 + 2], corr);
        corr = fmaf(exp2f(av.w * cum) * hv.w, sC[q * 4 + 3], corr);
    }
    float sr = res / (1.f + expf(-res));
    y[idx] = __float2bfloat16((yp + corr) * sr);
}

// ---------------------------------------------------------------------------
// Launch
// ---------------------------------------------------------------------------
extern "C" void kernel_launch(void* const* d_in, const int* in_sizes, int n_in,
                              void* d_out, int out_size, void* d_ws, size_t ws_size,
                              hipStream_t stream)
{
    const float* frames  = (const float*)d_in[0];
    const float* fproj_w = (const float*)d_in[1];
    const float* fproj_b = (const float*)d_in[2];
    const float* norm_w  = (const float*)d_in[3];
    const float* in_w    = (const float*)d_in[4];
    const float* conv_w  = (const float*)d_in[5];
    const float* conv_b  = (const float*)d_in[6];
    const float* xproj_w = (const float*)d_in[7];
    const float* dt_w    = (const float*)d_in[8];
    const float* dt_b    = (const float*)d_in[9];
    const float* A_log   = (const float*)d_in[10];
    const float* D_param = (const float*)d_in[11];
    const float* out_w   = (const float*)d_in[12];
    const float* normf_w = (const float*)d_in[13];

    // workspace layout
    char* ws = (char*)d_ws;
    float* h      = (float*)ws;                   ws += (size_t)M_TOK * D_MODEL * 4;
    float* xz     = (float*)ws;                   ws += (size_t)M_TOK * 2 * D_INNER * 4;
    float* xc     = (float*)ws;                   ws += (size_t)M_TOK * D_INNER * 4;
    float* xdbl   = (float*)ws;                   ws += (size_t)M_TOK * XPROJ_N * 4;
    float* delta  = (float*)ws;                   ws += (size_t)M_TOK * D_INNER * 4;
    float* part   = (float*)ws;                   ws += (size_t)KSPLIT * M_TOK * XPROJ_N * 4;
    float* A2b    = (float*)ws;                   ws += (size_t)D_INNER * 16 * 4;
    float* cumdv  = (float*)ws;                   ws += (size_t)M_TOK * D_INNER * 4;
    float* ypartb = (float*)ws;                   ws += (size_t)M_TOK * D_INNER * 4;
    float* hpartb = (float*)ws;                   ws += (size_t)BATCH * NCHUNK * D_INNER * 16 * 4;
    float* hinb   = (float*)ws;                   ws += (size_t)BATCH * NCHUNK * D_INNER * 16 * 4;
    __hip_bfloat16* x_bf   = (__hip_bfloat16*)ws; ws += (size_t)M_TOK * D_MODEL * 2;
    __hip_bfloat16* y_bf   = (__hip_bfloat16*)ws; ws += (size_t)M_TOK * D_INNER * 2;
    __hip_bfloat16* xc_bf  = (__hip_bfloat16*)ws; ws += (size_t)M_TOK * D_INNER * 2;
    __hip_bfloat16* dtin   = (__hip_bfloat16*)ws; ws += (size_t)M_TOK * 64 * 2;
    __hip_bfloat16* fr_bf  = (__hip_bfloat16*)ws; ws += (size_t)M_TOK * IMG_DIM * 2;
    __hip_bfloat16* fp_wT  = (__hip_bfloat16*)ws; ws += (size_t)D_MODEL * IMG_DIM * 2;
    __hip_bfloat16* in_wT  = (__hip_bfloat16*)ws; ws += (size_t)(2 * D_INNER) * D_MODEL * 2;
    __hip_bfloat16* out_wT = (__hip_bfloat16*)ws; ws += (size_t)D_MODEL * D_INNER * 2;
    __hip_bfloat16* xprojT = (__hip_bfloat16*)ws; ws += (size_t)XPROJ_N * D_INNER * 2;
    __hip_bfloat16* dt_wT  = (__hip_bfloat16*)ws; ws += (size_t)D_INNER * 64 * 2;

    dim3 blk(256);

    // zero dtin once per call (pad cols 48..63 must be 0)
    hipMemsetAsync(dtin, 0, (size_t)M_TOK * 64 * 2, stream);

    // h = relu(frames @ fproj_w + fproj_b)   (bf16 MFMA)
    cvt_bf16_k<<<(M_TOK * IMG_DIM) / 256, blk, 0, stream>>>(
        frames, fr_bf, M_TOK * IMG_DIM);
    wcvt_t_k<<<dim3(D_MODEL / 32, IMG_DIM / 32), blk, 0, stream>>>(
        fproj_w, fp_wT, IMG_DIM, D_MODEL);
    gemm_bf16<1><<<dim3(M_TOK / 64, D_MODEL / 64), blk, 0, stream>>>(
        fr_bf, fp_wT, h, D_MODEL, IMG_DIM, fproj_b);

    for (int i = 0; i < N_LAYER; ++i) {
        const float* in_wi    = in_w    + (size_t)i * D_MODEL * 2 * D_INNER;
        const float* conv_wi  = conv_w  + (size_t)i * D_INNER * D_CONV;
        const float* conv_bi  = conv_b  + (size_t)i * D_INNER;
        const float* xproj_wi = xproj_w + (size_t)i * D_INNER * XPROJ_N;
        const float* dt_wi    = dt_w    + (size_t)i * DT_RANK * D_INNER;
        const float* dt_bi    = dt_b    + (size_t)i * D_INNER;
        const float* A_logi   = A_log   + (size_t)i * D_INNER * D_STATE;
        const float* D_parami = D_param + (size_t)i * D_INNER;
        const float* out_wi   = out_w   + (size_t)i * D_INNER * D_MODEL;
        const float* norm_wi  = norm_w  + (size_t)i * D_MODEL;

        // x_bf = bf16(rmsnorm(h))
        rmsnorm_k<__hip_bfloat16><<<M_TOK, blk, 0, stream>>>(h, norm_wi, x_bf);
        // in_wT = bf16(in_w[i]^T)
        wcvt_t_k<<<dim3(2 * D_INNER / 32, D_MODEL / 32), blk, 0, stream>>>(
            in_wi, in_wT, D_MODEL, 2 * D_INNER);
        // xz = x_bf @ in_w[i]
        gemm_bf16<0><<<dim3(M_TOK / 64, (2 * D_INNER) / 64), blk, 0, stream>>>(
            x_bf, in_wT, xz, 2 * D_INNER, D_MODEL, nullptr);
        // xc = silu(conv(xi) + conv_b)  (+ bf16 copy)
        conv_silu_k<<<(M_TOK * D_INNER) / 256, blk, 0, stream>>>(
            xz, conv_wi, conv_bi, xc, xc_bf);
        // xprojT = bf16(xproj_w[i]^T)  [80][1536]
        wcvt_t_k<<<dim3((XPROJ_N + 31) / 32, D_INNER / 32), blk, 0, stream>>>(
            xproj_wi, xprojT, D_INNER, XPROJ_N);
        // xdbl = xc @ xproj_w[i]  (split-K MFMA + reduce)
        xproj_gemm_k<<<dim3(M_TOK / 64, KSPLIT), blk, 0, stream>>>(
            xc_bf, xprojT, part);
        xproj_reduce_k<<<(M_TOK * XPROJ_N) / 256, blk, 0, stream>>>(
            part, xdbl, dtin);
        // dt_wT = bf16 padded [1536][64]
        dtw_cvt_k<<<(D_INNER * 64) / 256, blk, 0, stream>>>(dt_wi, dt_wT);
        // delta = softplus(dtin @ dt_w[i] + dt_b[i])
        gemm_bf16<2><<<dim3(M_TOK / 64, D_INNER / 64), blk, 0, stream>>>(
            dtin, dt_wT, delta, D_INNER, 64, dt_bi);
        // chunked scan: A2, phase1 (partials), phase2 (prefix), phase3 (fix)
        a2_k<<<(D_INNER * 16) / 256, blk, 0, stream>>>(A_logi, A2b);
        scan_part_k<<<BATCH * NCHUNK * (D_INNER / 256), blk, 0, stream>>>(
            delta, xc, xdbl, A2b, D_parami, cumdv, ypartb, hpartb);
        scan_pref_k<<<(BATCH * D_INNER * 16) / 256, blk, 0, stream>>>(
            cumdv, hpartb, A2b, hinb);
        scan_fix_k<<<(M_TOK * D_INNER) / 256, blk, 0, stream>>>(
            ypartb, cumdv, xdbl, xz, A2b, hinb, y_bf);
        // out_wT = bf16(out_w[i]^T)
        wcvt_t_k<<<dim3(D_MODEL / 32, D_INNER / 32), blk, 0, stream>>>(
            out_wi, out_wT, D_INNER, D_MODEL);
        // h += y_bf @ out_w[i]
        gemm_bf16<3><<<dim3(M_TOK / 64, D_MODEL / 64), blk, 0, stream>>>(
            y_bf, out_wT, h, D_MODEL, D_INNER, nullptr);
    }

    // out = rmsnorm(h, normf_w)  (fp32)
    rmsnorm_k<float><<<M_TOK, blk, 0, stream>>>(h, normf_w, (float*)d_out);
}

// Round 7
// 1307.358 us; speedup vs baseline: 5.4491x; 1.0893x over previous
//
#include <hip/hip_runtime.h>
#include <hip/hip_bf16.h>
#include <cmath>

#define IMG_DIM 512
#define D_MODEL 768
#define N_LAYER 12
#define D_INNER 1536
#define D_STATE 16
#define D_CONV 4
#define DT_RANK 48
#define BATCH 4
#define SEQ 256
#define M_TOK (BATCH * SEQ)               // 1024 token rows
#define XPROJ_N (DT_RANK + 2 * D_STATE)   // 80
#define KSPLIT 8
#define NCHUNK 16
#define CLEN 16                           // SEQ / NCHUNK
#define LOG2E 1.4426950408889634f

typedef __attribute__((ext_vector_type(8))) short bf16x8;
typedef __attribute__((ext_vector_type(4))) float f32x4;
typedef __hip_bfloat16 bf16;

__device__ __forceinline__ float softplus_f(float v) {
    return v > 20.f ? v : log1pf(expf(v));
}
__device__ __forceinline__ float b2f(bf16 v) { return __bfloat162float(v); }

// ---------------------------------------------------------------------------
// Weight transpose + fp32->bf16: W[z][K][N] -> WT[z][N][K]; N-guarded.
// blockIdx.z = layer.
// ---------------------------------------------------------------------------
__global__ __launch_bounds__(256) void wcvt_t_k(
    const float* __restrict__ W, bf16* __restrict__ WT, int K, int N)
{
    __shared__ float tile[32][33];
    W  += (size_t)blockIdx.z * K * N;
    WT += (size_t)blockIdx.z * K * N;
    const int tx = threadIdx.x & 31;
    const int ty4 = (threadIdx.x >> 5) * 4;
    const int n0 = blockIdx.x * 32, k0 = blockIdx.y * 32;
    #pragma unroll
    for (int r = 0; r < 4; ++r)
        tile[ty4 + r][tx] = (n0 + tx < N)
            ? W[(size_t)(k0 + ty4 + r) * N + n0 + tx] : 0.f;
    __syncthreads();
    #pragma unroll
    for (int r = 0; r < 4; ++r)
        if (n0 + ty4 + r < N)
            WT[(size_t)(n0 + ty4 + r) * K + k0 + tx] =
                __float2bfloat16(tile[tx][ty4 + r]);
}

// ---------------------------------------------------------------------------
// Flat fp32 -> bf16 convert
// ---------------------------------------------------------------------------
__global__ __launch_bounds__(256) void cvt_bf16_k(
    const float* __restrict__ in, bf16* __restrict__ out, int n)
{
    int i = blockIdx.x * 256 + threadIdx.x;
    if (i < n) out[i] = __float2bfloat16(in[i]);
}

// ---------------------------------------------------------------------------
// dt_w (all layers) [12][48][1536] -> dt_wT [12][1536][64], zero-pad k 48..63
// ---------------------------------------------------------------------------
__global__ __launch_bounds__(256) void dtw_cvt_k(
    const float* __restrict__ dt_w, bf16* __restrict__ dtwT)
{
    int idx = blockIdx.x * 256 + threadIdx.x;   // over 12*1536*64
    int k = idx & 63;
    int n = (idx >> 6) % D_INNER;
    int l = idx / (64 * D_INNER);
    dtwT[idx] = (k < DT_RANK)
        ? __float2bfloat16(dt_w[((size_t)l * DT_RANK + k) * D_INNER + n])
        : bf16(0.f);
}

// ---------------------------------------------------------------------------
// A2 (all layers): A2[l][d][n] = -exp(A_log[l][d][n]) * log2(e)
// ---------------------------------------------------------------------------
__global__ __launch_bounds__(256) void a2_k(
    const float* __restrict__ A_log, float* __restrict__ A2)
{
    int idx = blockIdx.x * 256 + threadIdx.x;   // < 12*1536*16
    A2[idx] = -expf(A_log[idx]) * LOG2E;
}

// ---------------------------------------------------------------------------
// bf16 MFMA GEMM: C[M,N](OT) = A[M,K](bf16) @ BT[N,K](bf16)^T
// 64x64 tile, BK=64, 4 waves (2x2), XOR-swizzled LDS, reg-staged dbuf.
// EPI: 0 = store, 1 = bias+relu, 2 = bias+softplus, 3 = accumulate (OT=float)
// ---------------------------------------------------------------------------
template <int EPI, typename OT>
__global__ __launch_bounds__(256) void gemm_bf16(
    const bf16* __restrict__ A,
    const bf16* __restrict__ BT,
    OT* __restrict__ C, int ldc, int K,
    const float* __restrict__ bias)
{
    __shared__ __align__(16) char lds[2][16384];   // [buf][A 8K | B 8K]
    const int tid = threadIdx.x;
    const int lane = tid & 63;
    const int wid = tid >> 6;
    const int wr = wid >> 1, wc = wid & 1;
    const size_t rowBase = blockIdx.x * 64;
    const size_t colBase = blockIdx.y * 64;

    const int r0 = tid >> 3;
    const int cb0 = (tid & 7) * 16;
    const int wOffA = r0 * 128 + (cb0 ^ ((r0 & 7) << 4));
    const char* gA = (const char*)(A + rowBase * K);
    const char* gB = (const char*)(BT + colBase * K);
    const size_t rowByteOff = (size_t)r0 * K * 2 + cb0;

    const int lrow = lane & 15;
    const int kg = (lane >> 4) * 16;
    const int swz = (lane & 7) << 4;

    f32x4 acc[2][2] = {};

    const int nt = K >> 6;
    float4 ra0, ra1, rb0, rb1;

    ra0 = *(const float4*)(gA + rowByteOff);
    ra1 = *(const float4*)(gA + rowByteOff + (size_t)32 * K * 2);
    rb0 = *(const float4*)(gB + rowByteOff);
    rb1 = *(const float4*)(gB + rowByteOff + (size_t)32 * K * 2);
    *(float4*)(&lds[0][wOffA])        = ra0;
    *(float4*)(&lds[0][wOffA + 4096]) = ra1;
    *(float4*)(&lds[0][wOffA + 8192]) = rb0;
    *(float4*)(&lds[0][wOffA + 12288])= rb1;
    __syncthreads();

    for (int t = 0; t < nt; ++t) {
        const int cur = t & 1;
        if (t + 1 < nt) {
            size_t off = rowByteOff + (size_t)(t + 1) * 128;
            ra0 = *(const float4*)(gA + off);
            ra1 = *(const float4*)(gA + off + (size_t)32 * K * 2);
            rb0 = *(const float4*)(gB + off);
            rb1 = *(const float4*)(gB + off + (size_t)32 * K * 2);
        }
        #pragma unroll
        for (int kk = 0; kk < 2; ++kk) {
            const int col = (kk * 64 + kg) ^ swz;
            bf16x8 a0 = *(const bf16x8*)(&lds[cur][(wr * 32 +      lrow) * 128 + col]);
            bf16x8 a1 = *(const bf16x8*)(&lds[cur][(wr * 32 + 16 + lrow) * 128 + col]);
            bf16x8 b0 = *(const bf16x8*)(&lds[cur][8192 + (wc * 32 +      lrow) * 128 + col]);
            bf16x8 b1 = *(const bf16x8*)(&lds[cur][8192 + (wc * 32 + 16 + lrow) * 128 + col]);
            acc[0][0] = __builtin_amdgcn_mfma_f32_16x16x32_bf16(a0, b0, acc[0][0], 0, 0, 0);
            acc[0][1] = __builtin_amdgcn_mfma_f32_16x16x32_bf16(a0, b1, acc[0][1], 0, 0, 0);
            acc[1][0] = __builtin_amdgcn_mfma_f32_16x16x32_bf16(a1, b0, acc[1][0], 0, 0, 0);
            acc[1][1] = __builtin_amdgcn_mfma_f32_16x16x32_bf16(a1, b1, acc[1][1], 0, 0, 0);
        }
        if (t + 1 < nt) {
            const int nxt = cur ^ 1;
            *(float4*)(&lds[nxt][wOffA])        = ra0;
            *(float4*)(&lds[nxt][wOffA + 4096]) = ra1;
            *(float4*)(&lds[nxt][wOffA + 8192]) = rb0;
            *(float4*)(&lds[nxt][wOffA + 12288])= rb1;
        }
        __syncthreads();
    }

    const int mBase = (int)rowBase + wr * 32 + (lane >> 4) * 4;
    const int nBase = (int)colBase + wc * 32 + (lane & 15);
    #pragma unroll
    for (int i = 0; i < 2; ++i)
        #pragma unroll
        for (int j = 0; j < 2; ++j)
            #pragma unroll
            for (int rg = 0; rg < 4; ++rg) {
                int cc = nBase + j * 16;
                size_t idx = (size_t)(mBase + i * 16 + rg) * ldc + cc;
                float v = acc[i][j][rg];
                if (EPI == 0) {
                    C[idx] = (OT)v;
                } else if (EPI == 1) {
                    v += bias[cc];
                    C[idx] = (OT)(v > 0.f ? v : 0.f);
                } else if (EPI == 2) {
                    v += bias[cc];
                    C[idx] = (OT)softplus_f(v);
                } else {
                    C[idx] += v;
                }
            }
}

// ---------------------------------------------------------------------------
// Skinny split-K MFMA GEMM for xproj (no LDS)
// ---------------------------------------------------------------------------
__global__ __launch_bounds__(256) void xproj_gemm_k(
    const bf16* __restrict__ xc_bf,
    const bf16* __restrict__ xprojT,
    float* __restrict__ part)
{
    const int lane = threadIdx.x & 63;
    const int w = threadIdx.x >> 6;
    const int m0 = blockIdx.x * 64 + w * 16;
    const int ks = blockIdx.y;
    const int KS = D_INNER / KSPLIT;          // 192
    const int k0 = ks * KS;

    const int arow = m0 + (lane & 15);
    const int kgrp = (lane >> 4) * 8;

    f32x4 acc[5] = {};
    const bf16* ap = xc_bf + (size_t)arow * D_INNER + kgrp;
    const bf16* bp = xprojT + (size_t)(lane & 15) * D_INNER + kgrp;

    for (int k = k0; k < k0 + KS; k += 32) {
        bf16x8 a = *(const bf16x8*)(ap + k);
        #pragma unroll
        for (int f = 0; f < 5; ++f) {
            bf16x8 b = *(const bf16x8*)(bp + (size_t)f * 16 * D_INNER + k);
            acc[f] = __builtin_amdgcn_mfma_f32_16x16x32_bf16(a, b, acc[f], 0, 0, 0);
        }
    }

    float* out = part + (size_t)ks * M_TOK * XPROJ_N;
    const int rowb = blockIdx.x * 64 + w * 16 + (lane >> 4) * 4;
    #pragma unroll
    for (int f = 0; f < 5; ++f)
        #pragma unroll
        for (int rg = 0; rg < 4; ++rg)
            out[(size_t)(rowb + rg) * XPROJ_N + f * 16 + (lane & 15)] = acc[f][rg];
}

// ---------------------------------------------------------------------------
// Reduce split-K partials -> xdbl fp32 [1024][80]; cols<48 also -> dtin bf16
// ---------------------------------------------------------------------------
__global__ __launch_bounds__(256) void xproj_reduce_k(
    const float* __restrict__ part, float* __restrict__ xdbl,
    bf16* __restrict__ dtin)
{
    int idx = blockIdx.x * 256 + threadIdx.x;   // < 1024*80
    float s = 0.f;
    #pragma unroll
    for (int p = 0; p < KSPLIT; ++p)
        s += part[(size_t)p * M_TOK * XPROJ_N + idx];
    xdbl[idx] = s;
    int col = idx % XPROJ_N;
    int row = idx / XPROJ_N;
    if (col < DT_RANK)
        dtin[(size_t)row * 64 + col] = __float2bfloat16(s);
}

// ---------------------------------------------------------------------------
// RMSNorm: one block per token row; templated output type
// ---------------------------------------------------------------------------
template <typename OT>
__global__ __launch_bounds__(256) void rmsnorm_k(
    const float* __restrict__ x, const float* __restrict__ w,
    OT* __restrict__ o)
{
    const int row = blockIdx.x;
    const float* xr = x + (size_t)row * D_MODEL;
    float v[3];
    float s = 0.f;
    #pragma unroll
    for (int i = 0; i < 3; ++i) {
        v[i] = xr[threadIdx.x + i * 256];
        s = fmaf(v[i], v[i], s);
    }
    #pragma unroll
    for (int off = 32; off > 0; off >>= 1) s += __shfl_down(s, off);
    __shared__ float red[4];
    if ((threadIdx.x & 63) == 0) red[threadIdx.x >> 6] = s;
    __syncthreads();
    float tot = red[0] + red[1] + red[2] + red[3];
    float r = rsqrtf(tot * (1.f / D_MODEL) + 1e-5f);
    OT* orow = o + (size_t)row * D_MODEL;
    #pragma unroll
    for (int i = 0; i < 3; ++i) {
        int c = threadIdx.x + i * 256;
        orow[c] = (OT)(v[i] * r * w[c]);
    }
}

// ---------------------------------------------------------------------------
// Causal depthwise conv (width 4) + bias + silu; bf16 in (xz), bf16 out
// ---------------------------------------------------------------------------
__global__ __launch_bounds__(256) void conv_silu_k(
    const bf16* __restrict__ xz, const float* __restrict__ cw,
    const float* __restrict__ cb, bf16* __restrict__ xc_bf)
{
    int idx = blockIdx.x * 256 + threadIdx.x;
    int d = idx % D_INNER;
    int bt = idx / D_INNER;
    int t = bt & (SEQ - 1);
    int b = bt >> 8;
    float acc = cb[d];
    #pragma unroll
    for (int k = 0; k < 4; ++k) {
        int tt = t - 3 + k;
        if (tt >= 0)
            acc = fmaf(b2f(xz[(size_t)(b * SEQ + tt) * (2 * D_INNER) + d]),
                       cw[d * 4 + k], acc);
    }
    float sig = 1.f / (1.f + expf(-acc));
    xc_bf[idx] = __float2bfloat16(acc * sig);
}

// ---------------------------------------------------------------------------
// Chunked selective scan, phase 1: per (b, chunk, d) within-chunk scan from 0.
// bf16 delta/u inputs; fp32 state/outputs. No cross-lane ops.
// ---------------------------------------------------------------------------
__global__ __launch_bounds__(256) void scan_part_k(
    const bf16* __restrict__ delta,
    const bf16* __restrict__ xc,
    const float* __restrict__ xdbl,
    const float* __restrict__ A2,
    const float* __restrict__ D_param,
    float* __restrict__ cumdv,
    float* __restrict__ ypart,
    float* __restrict__ hpart)
{
    __shared__ float sBC[CLEN][32];   // [step][B 0..15 | C 16..31]
    const int tid = threadIdx.x;
    const int dgrp  = blockIdx.x % 6;
    const int chunk = (blockIdx.x / 6) & (NCHUNK - 1);
    const int b     = blockIdx.x / (6 * NCHUNK);
    const int d  = dgrp * 256 + tid;
    const int t0 = chunk * CLEN;

    {
        int r = tid >> 5, c = tid & 31;
        sBC[r][c]     = xdbl[(size_t)(b * SEQ + t0 + r) * XPROJ_N + DT_RANK + c];
        sBC[r + 8][c] = xdbl[(size_t)(b * SEQ + t0 + r + 8) * XPROJ_N + DT_RANK + c];
    }

    float a2[16];
    {
        const float4* ap = (const float4*)(A2 + (size_t)d * 16);
        #pragma unroll
        for (int q = 0; q < 4; ++q) {
            float4 v = ap[q];
            a2[q * 4 + 0] = v.x; a2[q * 4 + 1] = v.y;
            a2[q * 4 + 2] = v.z; a2[q * 4 + 3] = v.w;
        }
    }
    const float Dp = D_param[d];

    const size_t base = (size_t)(b * SEQ + t0) * D_INNER + d;
    const bf16* dp = delta + base;
    const bf16* up = xc + base;

    float dvv[CLEN], uvv[CLEN];
    #pragma unroll
    for (int s = 0; s < CLEN; ++s) {
        dvv[s] = b2f(dp[(size_t)s * D_INNER]);
        uvv[s] = b2f(up[(size_t)s * D_INNER]);
    }
    __syncthreads();

    float h[16];
    #pragma unroll
    for (int n = 0; n < 16; ++n) h[n] = 0.f;
    float cum = 0.f;

    #pragma unroll
    for (int s = 0; s < CLEN; ++s) {
        float dv = dvv[s], u = uvv[s];
        cum += dv;
        cumdv[base + (size_t)s * D_INNER] = cum;
        float du = dv * u;
        float yv = 0.f;
        #pragma unroll
        for (int n = 0; n < 16; ++n) {
            float dA = exp2f(dv * a2[n]);
            h[n] = fmaf(dA, h[n], du * sBC[s][n]);
            yv = fmaf(h[n], sBC[s][16 + n], yv);
        }
        ypart[base + (size_t)s * D_INNER] = fmaf(u, Dp, yv);
    }

    float4* hp = (float4*)(hpart + (((size_t)b * NCHUNK + chunk) * D_INNER + d) * 16);
    #pragma unroll
    for (int q = 0; q < 4; ++q) {
        float4 v;
        v.x = h[q * 4 + 0]; v.y = h[q * 4 + 1];
        v.z = h[q * 4 + 2]; v.w = h[q * 4 + 3];
        hp[q] = v;
    }
}

// ---------------------------------------------------------------------------
// Phase 2: serial prefix over chunks. Thread = (b,d,n).
// ---------------------------------------------------------------------------
__global__ __launch_bounds__(256) void scan_pref_k(
    const float* __restrict__ cumdv,
    const float* __restrict__ hpart,
    const float* __restrict__ A2,
    float* __restrict__ hinb)
{
    int idx = blockIdx.x * 256 + threadIdx.x;   // < 4*1536*16
    int n = idx & 15;
    int r = idx >> 4;
    int d = r % D_INNER;
    int b = r / D_INNER;
    float a2 = A2[(size_t)d * 16 + n];
    float hin = 0.f;
    #pragma unroll
    for (int c = 0; c < NCHUNK; ++c) {
        hinb[(((size_t)b * NCHUNK + c) * D_INNER + d) * 16 + n] = hin;
        float sdv = cumdv[(size_t)(b * SEQ + c * CLEN + CLEN - 1) * D_INNER + d];
        float hp  = hpart[(((size_t)b * NCHUNK + c) * D_INNER + d) * 16 + n];
        hin = fmaf(hin, exp2f(a2 * sdv), hp);
    }
}

// ---------------------------------------------------------------------------
// Phase 3: elementwise fix-up:
// y = (ypart + sum_n C[n]*exp2(A2[n]*cumdv)*hin[n]) * silu(res)
// ---------------------------------------------------------------------------
__global__ __launch_bounds__(256) void scan_fix_k(
    const float* __restrict__ ypart,
    const float* __restrict__ cumdv,
    const float* __restrict__ xdbl,
    const bf16* __restrict__ xz,
    const float* __restrict__ A2,
    const float* __restrict__ hinb,
    bf16* __restrict__ y)
{
    __shared__ float sC[16];
    int idx = blockIdx.x * 256 + threadIdx.x;   // bt constant per block
    int d = idx % D_INNER;
    int bt = idx / D_INNER;
    int t = bt & (SEQ - 1);
    int b = bt >> 8;
    int chunk = t >> 4;   // CLEN = 16

    if (threadIdx.x < 16)
        sC[threadIdx.x] = xdbl[(size_t)bt * XPROJ_N + DT_RANK + D_STATE + threadIdx.x];
    __syncthreads();

    float cum = cumdv[idx];
    float yp  = ypart[idx];
    float res = b2f(xz[(size_t)bt * 2 * D_INNER + D_INNER + d]);

    const float4* hp = (const float4*)(hinb + (((size_t)b * NCHUNK + chunk) * D_INNER + d) * 16);
    const float4* ap = (const float4*)(A2 + (size_t)d * 16);

    float corr = 0.f;
    #pragma unroll
    for (int q = 0; q < 4; ++q) {
        float4 hv = hp[q];
        float4 av = ap[q];
        corr = fmaf(exp2f(av.x * cum) * hv.x, sC[q * 4 + 0], corr);
        corr = fmaf(exp2f(av.y * cum) * hv.y, sC[q * 4 + 1], corr);
        corr = fmaf(exp2f(av.z * cum) * hv.z, sC[q * 4 + 2], corr);
        corr = fmaf(exp2f(av.w * cum) * hv.w, sC[q * 4 + 3], corr);
    }
    float sr = res / (1.f + expf(-res));
    y[idx] = __float2bfloat16((yp + corr) * sr);
}

// ---------------------------------------------------------------------------
// Launch
// ---------------------------------------------------------------------------
extern "C" void kernel_launch(void* const* d_in, const int* in_sizes, int n_in,
                              void* d_out, int out_size, void* d_ws, size_t ws_size,
                              hipStream_t stream)
{
    const float* frames  = (const float*)d_in[0];
    const float* fproj_w = (const float*)d_in[1];
    const float* fproj_b = (const float*)d_in[2];
    const float* norm_w  = (const float*)d_in[3];
    const float* in_w    = (const float*)d_in[4];
    const float* conv_w  = (const float*)d_in[5];
    const float* conv_b  = (const float*)d_in[6];
    const float* xproj_w = (const float*)d_in[7];
    const float* dt_w    = (const float*)d_in[8];
    const float* dt_b    = (const float*)d_in[9];
    const float* A_log   = (const float*)d_in[10];
    const float* D_param = (const float*)d_in[11];
    const float* out_w   = (const float*)d_in[12];
    const float* normf_w = (const float*)d_in[13];

    // workspace layout (~150 MB; harness ws is ~450 MB)
    char* ws = (char*)d_ws;
    float* h      = (float*)ws;        ws += (size_t)M_TOK * D_MODEL * 4;
    float* xdbl   = (float*)ws;        ws += (size_t)M_TOK * XPROJ_N * 4;
    float* part   = (float*)ws;        ws += (size_t)KSPLIT * M_TOK * XPROJ_N * 4;
    float* cumdv  = (float*)ws;        ws += (size_t)M_TOK * D_INNER * 4;
    float* ypartb = (float*)ws;        ws += (size_t)M_TOK * D_INNER * 4;
    float* hpartb = (float*)ws;        ws += (size_t)BATCH * NCHUNK * D_INNER * 16 * 4;
    float* hinb   = (float*)ws;        ws += (size_t)BATCH * NCHUNK * D_INNER * 16 * 4;
    float* A2all  = (float*)ws;        ws += (size_t)N_LAYER * D_INNER * 16 * 4;
    bf16* xz_bf   = (bf16*)ws;         ws += (size_t)M_TOK * 2 * D_INNER * 2;
    bf16* xc_bf   = (bf16*)ws;         ws += (size_t)M_TOK * D_INNER * 2;
    bf16* delta_bf= (bf16*)ws;         ws += (size_t)M_TOK * D_INNER * 2;
    bf16* x_bf    = (bf16*)ws;         ws += (size_t)M_TOK * D_MODEL * 2;
    bf16* y_bf    = (bf16*)ws;         ws += (size_t)M_TOK * D_INNER * 2;
    bf16* dtin    = (bf16*)ws;         ws += (size_t)M_TOK * 64 * 2;
    bf16* fr_bf   = (bf16*)ws;         ws += (size_t)M_TOK * IMG_DIM * 2;
    bf16* fp_wT   = (bf16*)ws;         ws += (size_t)D_MODEL * IMG_DIM * 2;
    bf16* in_wT   = (bf16*)ws;         ws += (size_t)N_LAYER * 2 * D_INNER * D_MODEL * 2;
    bf16* out_wT  = (bf16*)ws;         ws += (size_t)N_LAYER * D_MODEL * D_INNER * 2;
    bf16* xprojT  = (bf16*)ws;         ws += (size_t)N_LAYER * XPROJ_N * D_INNER * 2;
    bf16* dt_wT   = (bf16*)ws;         ws += (size_t)N_LAYER * D_INNER * 64 * 2;

    dim3 blk(256);

    // --- once-per-call preprocessing (batched over all layers) ---
    hipMemsetAsync(dtin, 0, (size_t)M_TOK * 64 * 2, stream);
    cvt_bf16_k<<<(M_TOK * IMG_DIM) / 256, blk, 0, stream>>>(
        frames, fr_bf, M_TOK * IMG_DIM);
    wcvt_t_k<<<dim3(D_MODEL / 32, IMG_DIM / 32, 1), blk, 0, stream>>>(
        fproj_w, fp_wT, IMG_DIM, D_MODEL);
    wcvt_t_k<<<dim3(2 * D_INNER / 32, D_MODEL / 32, N_LAYER), blk, 0, stream>>>(
        in_w, in_wT, D_MODEL, 2 * D_INNER);
    wcvt_t_k<<<dim3(D_MODEL / 32, D_INNER / 32, N_LAYER), blk, 0, stream>>>(
        out_w, out_wT, D_INNER, D_MODEL);
    wcvt_t_k<<<dim3((XPROJ_N + 31) / 32, D_INNER / 32, N_LAYER), blk, 0, stream>>>(
        xproj_w, xprojT, D_INNER, XPROJ_N);
    dtw_cvt_k<<<(N_LAYER * D_INNER * 64) / 256, blk, 0, stream>>>(dt_w, dt_wT);
    a2_k<<<(N_LAYER * D_INNER * 16) / 256, blk, 0, stream>>>(A_log, A2all);

    // h = relu(frames @ fproj_w + fproj_b)
    gemm_bf16<1, float><<<dim3(M_TOK / 64, D_MODEL / 64), blk, 0, stream>>>(
        fr_bf, fp_wT, h, D_MODEL, IMG_DIM, fproj_b);

    for (int i = 0; i < N_LAYER; ++i) {
        const bf16* in_wTi   = in_wT  + (size_t)i * 2 * D_INNER * D_MODEL;
        const bf16* out_wTi  = out_wT + (size_t)i * D_MODEL * D_INNER;
        const bf16* xprojTi  = xprojT + (size_t)i * XPROJ_N * D_INNER;
        const bf16* dt_wTi   = dt_wT  + (size_t)i * D_INNER * 64;
        const float* A2i     = A2all  + (size_t)i * D_INNER * 16;
        const float* conv_wi = conv_w + (size_t)i * D_INNER * D_CONV;
        const float* conv_bi = conv_b + (size_t)i * D_INNER;
        const float* dt_bi   = dt_b   + (size_t)i * D_INNER;
        const float* D_parami= D_param+ (size_t)i * D_INNER;
        const float* norm_wi = norm_w + (size_t)i * D_MODEL;

        rmsnorm_k<bf16><<<M_TOK, blk, 0, stream>>>(h, norm_wi, x_bf);
        gemm_bf16<0, bf16><<<dim3(M_TOK / 64, (2 * D_INNER) / 64), blk, 0, stream>>>(
            x_bf, in_wTi, xz_bf, 2 * D_INNER, D_MODEL, nullptr);
        conv_silu_k<<<(M_TOK * D_INNER) / 256, blk, 0, stream>>>(
            xz_bf, conv_wi, conv_bi, xc_bf);
        xproj_gemm_k<<<dim3(M_TOK / 64, KSPLIT), blk, 0, stream>>>(
            xc_bf, xprojTi, part);
        xproj_reduce_k<<<(M_TOK * XPROJ_N) / 256, blk, 0, stream>>>(
            part, xdbl, dtin);
        gemm_bf16<2, bf16><<<dim3(M_TOK / 64, D_INNER / 64), blk, 0, stream>>>(
            dtin, dt_wTi, delta_bf, D_INNER, 64, dt_bi);
        scan_part_k<<<BATCH * NCHUNK * (D_INNER / 256), blk, 0, stream>>>(
            delta_bf, xc_bf, xdbl, A2i, D_parami, cumdv, ypartb, hpartb);
        scan_pref_k<<<(BATCH * D_INNER * 16) / 256, blk, 0, stream>>>(
            cumdv, hpartb, A2i, hinb);
        scan_fix_k<<<(M_TOK * D_INNER) / 256, blk, 0, stream>>>(
            ypartb, cumdv, xdbl, xz_bf, A2i, hinb, y_bf);
        gemm_bf16<3, float><<<dim3(M_TOK / 64, D_MODEL / 64), blk, 0, stream>>>(
            y_bf, out_wTi, h, D_MODEL, D_INNER, nullptr);
    }

    // out = rmsnorm(h, normf_w)  (fp32)
    rmsnorm_k<float><<<M_TOK, blk, 0, stream>>>(h, normf_w, (float*)d_out);
}